// Round 6
// baseline (652.330 us; speedup 1.0000x reference)
//
#include <hip/hip_runtime.h>

// GCN 2-layer: x[N,128] -> GCNConv(W1[128,64], b1) -> ReLU -> GCNConv(W2[64,32], b2)
// norm = dinv[src]*dinv[dst] factorized: pre-scale h by dinv, aggregate, post-scale.
// CSR build via bucketed multisplit (R4). bf16 intermediates (R5).
// R6: register-tiled fp32 GEMMs (4x4 acc/thread, b128 LDS reads) -- R5 showed
// k_gemm1 VALU-issue-bound at ~40% FMA density (53us vs 10.4us FMA floor).

#define BLK 256
#define EPT 8            // edges/thread in hist & part
#define BSHIFT 10        // nodes per bucket
#define NPB 1024         // 1 << BSHIFT
#define MAXBUCK 128      // >= nbuck = ceil(N / NPB); N=100K -> 98

typedef unsigned int uint_t;
typedef unsigned short ushort_t;

__device__ __forceinline__ ushort_t f2bf(float x) {   // RNE float->bf16
    union { float f; uint_t u; } un; un.f = x;
    uint_t u = un.u;
    return (ushort_t)((u + 0x7fffu + ((u >> 16) & 1u)) >> 16);
}
__device__ __forceinline__ void bfacc(float* a, uint4 v) {  // 8 bf16 += into fp32
    a[0] += __uint_as_float(v.x << 16);
    a[1] += __uint_as_float(v.x & 0xffff0000u);
    a[2] += __uint_as_float(v.y << 16);
    a[3] += __uint_as_float(v.y & 0xffff0000u);
    a[4] += __uint_as_float(v.z << 16);
    a[5] += __uint_as_float(v.z & 0xffff0000u);
    a[6] += __uint_as_float(v.w << 16);
    a[7] += __uint_as_float(v.w & 0xffff0000u);
}

// int64-layout detection (wave-uniform, L2-hot): odd 32-bit words of the first
// 16 index values are all zero iff indices are little-endian int64.
__device__ __forceinline__ bool detect64(const int* __restrict__ idx) {
    int z = 0;
#pragma unroll
    for (int i = 1; i < 32; i += 2) z |= idx[i];
    return z == 0;
}

// ---- pass A: per-bucket histogram (LDS-accumulated, 1 global atomic/bucket/block)
__global__ void k_hist(const int* __restrict__ idx, int* __restrict__ bucket_counts,
                       int E) {
    __shared__ int h[MAXBUCK];
    bool is64 = detect64(idx);
    for (int i = threadIdx.x; i < MAXBUCK; i += BLK) h[i] = 0;
    __syncthreads();
    int base = blockIdx.x * (BLK * EPT) + threadIdx.x;
#pragma unroll
    for (int k = 0; k < EPT; ++k) {
        int e = base + k * BLK;
        if (e < E) {
            int d = is64 ? idx[2 * (E + e)] : idx[E + e];
            atomicAdd(&h[d >> BSHIFT], 1);
        }
    }
    __syncthreads();
    for (int i = threadIdx.x; i < MAXBUCK; i += BLK)
        if (h[i]) atomicAdd(&bucket_counts[i], h[i]);
}

// ---- scan bucket counts -> bucket_base[nbuck+1], init cursors
__global__ void k_bscan(const int* __restrict__ bucket_counts, int* __restrict__ bucket_base,
                        int* __restrict__ bucket_cursor, int nbuck, int E) {
    __shared__ int s[MAXBUCK];
    int t = threadIdx.x;  // MAXBUCK threads
    s[t] = (t < nbuck) ? bucket_counts[t] : 0;
    __syncthreads();
    for (int st = 1; st < MAXBUCK; st <<= 1) {
        int v = (t >= st) ? s[t - st] : 0;
        __syncthreads();
        s[t] += v;
        __syncthreads();
    }
    int excl = (t == 0) ? 0 : s[t - 1];
    if (t < nbuck) { bucket_base[t] = excl; bucket_cursor[t] = excl; }
    if (t == 0) bucket_base[nbuck] = E;
}

// ---- pass B: partition edges by bucket; packed value = src | (dst&1023)<<17.
__global__ void k_part(const int* __restrict__ idx, int* __restrict__ bucket_cursor,
                       int* __restrict__ edge_part, int E) {
    __shared__ int h[MAXBUCK];
    __shared__ int rbase[MAXBUCK];
    bool is64 = detect64(idx);
    for (int i = threadIdx.x; i < MAXBUCK; i += BLK) h[i] = 0;
    __syncthreads();
    int base = blockIdx.x * (BLK * EPT) + threadIdx.x;
    int dst[EPT], src[EPT];
#pragma unroll
    for (int k = 0; k < EPT; ++k) {
        int e = base + k * BLK;
        if (e < E) {
            dst[k] = is64 ? idx[2 * (E + e)] : idx[E + e];
            src[k] = is64 ? idx[2 * e] : idx[e];
            atomicAdd(&h[dst[k] >> BSHIFT], 1);
        } else {
            dst[k] = -1;
        }
    }
    __syncthreads();
    for (int i = threadIdx.x; i < MAXBUCK; i += BLK) {
        int c = h[i];
        rbase[i] = c ? atomicAdd(&bucket_cursor[i], c) : 0;
        h[i] = 0;
    }
    __syncthreads();
#pragma unroll
    for (int k = 0; k < EPT; ++k) {
        if (dst[k] >= 0) {
            int b = dst[k] >> BSHIFT;
            int r = atomicAdd(&h[b], 1);
            edge_part[rbase[b] + r] = src[k] | ((dst[k] & (NPB - 1)) << 17);
        }
    }
}

// ---- pass C: one workgroup per bucket; per-node count/scan/cursor in LDS;
// emits row_ptr, dinv, csr_src (random stores confined to this CU's ~64KB region).
__global__ void k_csr(const int* __restrict__ edge_part, const int* __restrict__ bucket_base,
                      int* __restrict__ row_ptr, float* __restrict__ dinv,
                      int* __restrict__ csr_src, int N, int E, int nbuck) {
    __shared__ int cnt[NPB];
    __shared__ int off[NPB];
    __shared__ int tsum[BLK];
    int b = blockIdx.x;
    int node0 = b << BSHIFT;
    int nn = min(NPB, N - node0);
    int ebeg = bucket_base[b], eend = bucket_base[b + 1];
    int t = threadIdx.x;
    for (int i = t; i < NPB; i += BLK) cnt[i] = 0;
    __syncthreads();
    for (int e = ebeg + t; e < eend; e += BLK)
        atomicAdd(&cnt[((unsigned)edge_part[e]) >> 17], 1);
    __syncthreads();
    int c0 = cnt[4 * t], c1 = cnt[4 * t + 1], c2 = cnt[4 * t + 2], c3 = cnt[4 * t + 3];
    tsum[t] = c0 + c1 + c2 + c3;
    __syncthreads();
    for (int st = 1; st < BLK; st <<= 1) {
        int v = (t >= st) ? tsum[t - st] : 0;
        __syncthreads();
        tsum[t] += v;
        __syncthreads();
    }
    int ex = (t == 0) ? 0 : tsum[t - 1];
    off[4 * t] = ex;
    off[4 * t + 1] = ex + c0;
    off[4 * t + 2] = ex + c0 + c1;
    off[4 * t + 3] = ex + c0 + c1 + c2;
    __syncthreads();
    for (int i = t; i < nn; i += BLK) {
        row_ptr[node0 + i] = ebeg + off[i];
        dinv[node0 + i] = rsqrtf((float)(cnt[i] + 1));  // +1 self-loop
    }
    if (b == nbuck - 1 && t == 0) row_ptr[N] = E;
    __syncthreads();
    for (int e = ebeg + t; e < eend; e += BLK) {
        int p = edge_part[e];
        int dlo = ((unsigned)p) >> 17;
        int r = atomicAdd(&off[dlo], 1);
        csr_src[ebeg + r] = p & 0x1FFFF;
    }
}

// ---- layer 1 GEMM (register-tiled): 64 rows x 64 cols per block, 4x4 per thread.
// hs1[i,f] = bf16((x @ W1)[i,f] * dinv[i])
__global__ void k_gemm1(const float* __restrict__ x, const float* __restrict__ W1,
                        const float* __restrict__ dinv, ushort_t* __restrict__ hs1, int N) {
    __shared__ float xs[64][64];     // 16 KB: one 64-wide K-chunk of the x tile
    __shared__ float wT[64][132];    // 33.8 KB: transposed W1 (full K), +4 pad
    int t = threadIdx.x;
    int rbase = blockIdx.x * 64;
    // stage W1 transposed: wT[c][k] = W1[k][c]
    for (int i = t; i < 2048; i += BLK) {
        int k = i >> 4, c4 = i & 15;
        float4 w = ((const float4*)W1)[i];
        wT[4 * c4 + 0][k] = w.x; wT[4 * c4 + 1][k] = w.y;
        wT[4 * c4 + 2][k] = w.z; wT[4 * c4 + 3][k] = w.w;
    }
    int tx = t & 15, ty = t >> 4;    // tx: col group (4 cols), ty: row group (4 rows)
    float acc[4][4] = {{0.f, 0.f, 0.f, 0.f}, {0.f, 0.f, 0.f, 0.f},
                       {0.f, 0.f, 0.f, 0.f}, {0.f, 0.f, 0.f, 0.f}};
    const float4* xv = (const float4*)x;
    for (int kb = 0; kb < 128; kb += 64) {
        __syncthreads();             // also covers wT staging on first pass
        for (int i = t; i < 1024; i += BLK) {
            int r = i >> 4, c = i & 15;
            int rr = rbase + r; if (rr >= N) rr = N - 1;
            ((float4*)&xs[r][0])[c] = xv[(size_t)rr * 32 + (kb >> 2) + c];
        }
        __syncthreads();
#pragma unroll
        for (int k0 = 0; k0 < 64; k0 += 4) {
            float4 xr[4], wr[4];
#pragma unroll
            for (int i = 0; i < 4; ++i) xr[i] = *(const float4*)&xs[4 * ty + i][k0];
#pragma unroll
            for (int j = 0; j < 4; ++j) wr[j] = *(const float4*)&wT[4 * tx + j][kb + k0];
#pragma unroll
            for (int i = 0; i < 4; ++i)
#pragma unroll
                for (int j = 0; j < 4; ++j) {
                    acc[i][j] = fmaf(xr[i].x, wr[j].x, acc[i][j]);
                    acc[i][j] = fmaf(xr[i].y, wr[j].y, acc[i][j]);
                    acc[i][j] = fmaf(xr[i].z, wr[j].z, acc[i][j]);
                    acc[i][j] = fmaf(xr[i].w, wr[j].w, acc[i][j]);
                }
        }
    }
#pragma unroll
    for (int i = 0; i < 4; ++i) {
        int r = rbase + 4 * ty + i;
        if (r < N) {
            float s = dinv[r];
            uint_t p0 = f2bf(acc[i][0] * s) | ((uint_t)f2bf(acc[i][1] * s) << 16);
            uint_t p1 = f2bf(acc[i][2] * s) | ((uint_t)f2bf(acc[i][3] * s) << 16);
            uint2 o; o.x = p0; o.y = p1;
            *(uint2*)&hs1[(size_t)r * 64 + 4 * tx] = o;
        }
    }
}

// ---- layer 1 aggregation: one wave per node; 8 groups x 8 lanes, each lane a
// uint4 (8 bf16); unroll 2 -> 16 independent 128B row gathers in flight.
__global__ void k_agg1(const uint_t* __restrict__ hs1, const int* __restrict__ row_ptr,
                       const int* __restrict__ csr_src, const float* __restrict__ dinv,
                       const float* __restrict__ b1, float* __restrict__ a1, int N) {
    int node = (blockIdx.x * blockDim.x + threadIdx.x) >> 6;
    if (node >= N) return;
    int lane = threadIdx.x & 63;
    int g = lane >> 3;   // edge slot 0..7
    int c = lane & 7;    // uint4 column: features [8c, 8c+8)
    const uint4* H = (const uint4*)hs1;  // row i at H[i*8 + c]

    float acc[8] = {0.f, 0.f, 0.f, 0.f, 0.f, 0.f, 0.f, 0.f};
    if (g == 0) bfacc(acc, H[(size_t)node * 8 + c]);  // self-loop (pre-scaled)

    int beg = row_ptr[node], end = row_ptr[node + 1];
    int e = beg + g;
    for (; e + 8 < end; e += 16) {
        int j0 = csr_src[e];
        int j1 = csr_src[e + 8];
        uint4 v0 = H[(size_t)j0 * 8 + c];
        uint4 v1 = H[(size_t)j1 * 8 + c];
        bfacc(acc, v0);
        bfacc(acc, v1);
    }
    if (e < end) {
        int j = csr_src[e];
        bfacc(acc, H[(size_t)j * 8 + c]);
    }
#pragma unroll
    for (int m = 8; m <= 32; m <<= 1)
#pragma unroll
        for (int i = 0; i < 8; ++i) acc[i] += __shfl_xor(acc[i], m, 64);
    if (g == 0) {
        float s = dinv[node];
        const float4* B = (const float4*)b1;
        float4 bv0 = B[2 * c], bv1 = B[2 * c + 1];
        float4 o0, o1;
        o0.x = fmaxf(fmaf(acc[0], s, bv0.x), 0.f);
        o0.y = fmaxf(fmaf(acc[1], s, bv0.y), 0.f);
        o0.z = fmaxf(fmaf(acc[2], s, bv0.z), 0.f);
        o0.w = fmaxf(fmaf(acc[3], s, bv0.w), 0.f);
        o1.x = fmaxf(fmaf(acc[4], s, bv1.x), 0.f);
        o1.y = fmaxf(fmaf(acc[5], s, bv1.y), 0.f);
        o1.z = fmaxf(fmaf(acc[6], s, bv1.z), 0.f);
        o1.w = fmaxf(fmaf(acc[7], s, bv1.w), 0.f);
        float4* A = (float4*)a1;
        A[(size_t)node * 16 + 2 * c] = o0;
        A[(size_t)node * 16 + 2 * c + 1] = o1;
    }
}

// ---- layer 2 GEMM (register-tiled): 128 rows x 32 cols per block, 4x4 per thread.
// hs2[i,f] = bf16((a1 @ W2)[i,f] * dinv[i])
__global__ void k_gemm2(const float* __restrict__ a1, const float* __restrict__ W2,
                        const float* __restrict__ dinv, ushort_t* __restrict__ hs2, int N) {
    __shared__ float as[128][64];    // 32 KB
    __shared__ float wT[32][68];     // 8.7 KB: transposed W2, +4 pad
    int t = threadIdx.x;
    int rbase = blockIdx.x * 128;
    for (int i = t; i < 512; i += BLK) {
        int k = i >> 3, c4 = i & 7;
        float4 w = ((const float4*)W2)[i];
        wT[4 * c4 + 0][k] = w.x; wT[4 * c4 + 1][k] = w.y;
        wT[4 * c4 + 2][k] = w.z; wT[4 * c4 + 3][k] = w.w;
    }
    const float4* av = (const float4*)a1;
    for (int i = t; i < 2048; i += BLK) {
        int r = i >> 4, c = i & 15;
        int rr = rbase + r; if (rr >= N) rr = N - 1;
        ((float4*)&as[r][0])[c] = av[(size_t)rr * 16 + c];
    }
    __syncthreads();
    int tx = t & 7, ty = t >> 3;     // tx: col group (4 of 32 cols), ty: row group (4 of 128 rows)
    float acc[4][4] = {{0.f, 0.f, 0.f, 0.f}, {0.f, 0.f, 0.f, 0.f},
                       {0.f, 0.f, 0.f, 0.f}, {0.f, 0.f, 0.f, 0.f}};
#pragma unroll
    for (int k0 = 0; k0 < 64; k0 += 4) {
        float4 xr[4], wr[4];
#pragma unroll
        for (int i = 0; i < 4; ++i) xr[i] = *(const float4*)&as[4 * ty + i][k0];
#pragma unroll
        for (int j = 0; j < 4; ++j) wr[j] = *(const float4*)&wT[4 * tx + j][k0];
#pragma unroll
        for (int i = 0; i < 4; ++i)
#pragma unroll
            for (int j = 0; j < 4; ++j) {
                acc[i][j] = fmaf(xr[i].x, wr[j].x, acc[i][j]);
                acc[i][j] = fmaf(xr[i].y, wr[j].y, acc[i][j]);
                acc[i][j] = fmaf(xr[i].z, wr[j].z, acc[i][j]);
                acc[i][j] = fmaf(xr[i].w, wr[j].w, acc[i][j]);
            }
    }
#pragma unroll
    for (int i = 0; i < 4; ++i) {
        int r = rbase + 4 * ty + i;
        if (r < N) {
            float s = dinv[r];
            uint_t p0 = f2bf(acc[i][0] * s) | ((uint_t)f2bf(acc[i][1] * s) << 16);
            uint_t p1 = f2bf(acc[i][2] * s) | ((uint_t)f2bf(acc[i][3] * s) << 16);
            uint2 o; o.x = p0; o.y = p1;
            *(uint2*)&hs2[(size_t)r * 32 + 4 * tx] = o;
        }
    }
}

// ---- layer 2 aggregation: 16 groups x 4 lanes (64B bf16 rows), unroll 2
// -> up to 32 independent row gathers in flight.
__global__ void k_agg2(const uint_t* __restrict__ hs2, const int* __restrict__ row_ptr,
                       const int* __restrict__ csr_src, const float* __restrict__ dinv,
                       const float* __restrict__ b2, float* __restrict__ out, int N) {
    int node = (blockIdx.x * blockDim.x + threadIdx.x) >> 6;
    if (node >= N) return;
    int lane = threadIdx.x & 63;
    int g = lane >> 2;   // edge slot 0..15
    int c = lane & 3;    // uint4 column: features [8c, 8c+8)
    const uint4* H = (const uint4*)hs2;  // row i at H[i*4 + c]

    float acc[8] = {0.f, 0.f, 0.f, 0.f, 0.f, 0.f, 0.f, 0.f};
    if (g == 0) bfacc(acc, H[(size_t)node * 4 + c]);  // self-loop

    int beg = row_ptr[node], end = row_ptr[node + 1];
    int e = beg + g;
    for (; e + 16 < end; e += 32) {
        int j0 = csr_src[e];
        int j1 = csr_src[e + 16];
        uint4 v0 = H[(size_t)j0 * 4 + c];
        uint4 v1 = H[(size_t)j1 * 4 + c];
        bfacc(acc, v0);
        bfacc(acc, v1);
    }
    if (e < end) {
        int j = csr_src[e];
        bfacc(acc, H[(size_t)j * 4 + c]);
    }
#pragma unroll
    for (int m = 4; m <= 32; m <<= 1)
#pragma unroll
        for (int i = 0; i < 8; ++i) acc[i] += __shfl_xor(acc[i], m, 64);
    if (g == 0) {
        float s = dinv[node];
        const float4* B = (const float4*)b2;
        float4 bv0 = B[2 * c], bv1 = B[2 * c + 1];
        float4 o0, o1;
        o0.x = fmaf(acc[0], s, bv0.x);
        o0.y = fmaf(acc[1], s, bv0.y);
        o0.z = fmaf(acc[2], s, bv0.z);
        o0.w = fmaf(acc[3], s, bv0.w);
        o1.x = fmaf(acc[4], s, bv1.x);
        o1.y = fmaf(acc[5], s, bv1.y);
        o1.z = fmaf(acc[6], s, bv1.z);
        o1.w = fmaf(acc[7], s, bv1.w);
        float4* O = (float4*)out;
        O[(size_t)node * 8 + 2 * c] = o0;
        O[(size_t)node * 8 + 2 * c + 1] = o1;
    }
}

extern "C" void kernel_launch(void* const* d_in, const int* in_sizes, int n_in,
                              void* d_out, int out_size, void* d_ws, size_t ws_size,
                              hipStream_t stream) {
    const float* x  = (const float*)d_in[0];
    const int*   idx = (const int*)d_in[1];
    const float* W1 = (const float*)d_in[2];
    const float* b1 = (const float*)d_in[3];
    const float* W2 = (const float*)d_in[4];
    const float* b2 = (const float*)d_in[5];
    float* out = (float*)d_out;

    const int N = in_sizes[0] / 128;   // 100000 (< 2^17, required by packing)
    const int E = in_sizes[1] / 2;     // 1600000
    const int nbuck = (N + NPB - 1) >> BSHIFT;   // 98 (<= MAXBUCK)

    // workspace layout (256B aligned)
    char* ws = (char*)d_ws;
    size_t off = 0;
    auto alloc = [&](size_t bytes) -> char* {
        char* p = ws + off;
        off = (off + bytes + 255) & ~(size_t)255;
        return p;
    };
    float* dinv     = (float*)alloc((size_t)N * 4);
    int*   row_ptr  = (int*)alloc((size_t)(N + 1) * 4);
    int*   bcounts  = (int*)alloc(MAXBUCK * 4);
    int*   bbase    = (int*)alloc((MAXBUCK + 1) * 4);
    int*   bcursor  = (int*)alloc(MAXBUCK * 4);
    int*   csr_src  = (int*)alloc((size_t)E * 4);
    ushort_t* hs1   = (ushort_t*)alloc((size_t)N * 64 * 2);  // bf16
    float* a1       = (float*)alloc((size_t)N * 64 * 4);
    ushort_t* hs2   = hs1;               // reuse: hs1 dead after k_agg1
    int*   edge_part = (int*)hs1;        // reuse: hs1 written only at k_gemm1

    const int ebk = (E + BLK * EPT - 1) / (BLK * EPT);  // 782

    hipMemsetAsync(bcounts, 0, MAXBUCK * 4, stream);
    k_hist<<<ebk, BLK, 0, stream>>>(idx, bcounts, E);
    k_bscan<<<1, MAXBUCK, 0, stream>>>(bcounts, bbase, bcursor, nbuck, E);
    k_part<<<ebk, BLK, 0, stream>>>(idx, bcursor, edge_part, E);
    k_csr<<<nbuck, BLK, 0, stream>>>(edge_part, bbase, row_ptr, dinv, csr_src, N, E, nbuck);

    k_gemm1<<<(N + 63) / 64, 256, 0, stream>>>(x, W1, dinv, hs1, N);
    k_agg1<<<(N + 3) / 4, 256, 0, stream>>>((const uint_t*)hs1, row_ptr, csr_src, dinv, b1, a1, N);
    k_gemm2<<<(N + 127) / 128, 256, 0, stream>>>(a1, W2, dinv, hs2, N);
    k_agg2<<<(N + 3) / 4, 256, 0, stream>>>((const uint_t*)hs2, row_ptr, csr_src, dinv, b2, out, N);
}

// Round 7
// 319.316 us; speedup vs baseline: 2.0429x; 2.0429x over previous
//
#include <hip/hip_runtime.h>

// GCN 2-layer: x[N,128] -> GCNConv(W1[128,64], b1) -> ReLU -> GCNConv(W2[64,32], b2)
// norm = dinv[src]*dinv[dst] factorized: pre-scale h by dinv, aggregate, post-scale.
// CSR build via bucketed multisplit (R4). bf16 intermediates (R5).
// R7: register-tiled GEMMs redone after R6 spill disaster (FETCH 401MB = scratch;
// arrays not SROA'd -> named scalars only) and bank-conflict fix (strided row/col
// ownership: consecutive-4 ownership provably conflicts for any aligned stride).

#define BLK 256
#define EPT 8            // edges/thread in hist & part
#define BSHIFT 10        // nodes per bucket
#define NPB 1024         // 1 << BSHIFT
#define MAXBUCK 128      // >= nbuck = ceil(N / NPB); N=100K -> 98

typedef unsigned int uint_t;
typedef unsigned short ushort_t;

__device__ __forceinline__ uint_t f2bf(float x) {   // RNE float->bf16 (low 16)
    union { float f; uint_t u; } un; un.f = x;
    uint_t u = un.u;
    return (u + 0x7fffu + ((u >> 16) & 1u)) >> 16;
}
__device__ __forceinline__ void bfacc(float* a, uint4 v) {  // 8 bf16 += into fp32
    a[0] += __uint_as_float(v.x << 16);
    a[1] += __uint_as_float(v.x & 0xffff0000u);
    a[2] += __uint_as_float(v.y << 16);
    a[3] += __uint_as_float(v.y & 0xffff0000u);
    a[4] += __uint_as_float(v.z << 16);
    a[5] += __uint_as_float(v.z & 0xffff0000u);
    a[6] += __uint_as_float(v.w << 16);
    a[7] += __uint_as_float(v.w & 0xffff0000u);
}

#define DOT4(acc, xv, wv)                 \
    acc = fmaf((xv).x, (wv).x, acc);      \
    acc = fmaf((xv).y, (wv).y, acc);      \
    acc = fmaf((xv).z, (wv).z, acc);      \
    acc = fmaf((xv).w, (wv).w, acc)

// int64-layout detection (wave-uniform, L2-hot): odd 32-bit words of the first
// 16 index values are all zero iff indices are little-endian int64.
__device__ __forceinline__ bool detect64(const int* __restrict__ idx) {
    int z = 0;
#pragma unroll
    for (int i = 1; i < 32; i += 2) z |= idx[i];
    return z == 0;
}

// ---- pass A: per-bucket histogram (LDS-accumulated, 1 global atomic/bucket/block)
__global__ void k_hist(const int* __restrict__ idx, int* __restrict__ bucket_counts,
                       int E) {
    __shared__ int h[MAXBUCK];
    bool is64 = detect64(idx);
    for (int i = threadIdx.x; i < MAXBUCK; i += BLK) h[i] = 0;
    __syncthreads();
    int base = blockIdx.x * (BLK * EPT) + threadIdx.x;
#pragma unroll
    for (int k = 0; k < EPT; ++k) {
        int e = base + k * BLK;
        if (e < E) {
            int d = is64 ? idx[2 * (E + e)] : idx[E + e];
            atomicAdd(&h[d >> BSHIFT], 1);
        }
    }
    __syncthreads();
    for (int i = threadIdx.x; i < MAXBUCK; i += BLK)
        if (h[i]) atomicAdd(&bucket_counts[i], h[i]);
}

// ---- scan bucket counts -> bucket_base[nbuck+1], init cursors
__global__ void k_bscan(const int* __restrict__ bucket_counts, int* __restrict__ bucket_base,
                        int* __restrict__ bucket_cursor, int nbuck, int E) {
    __shared__ int s[MAXBUCK];
    int t = threadIdx.x;  // MAXBUCK threads
    s[t] = (t < nbuck) ? bucket_counts[t] : 0;
    __syncthreads();
    for (int st = 1; st < MAXBUCK; st <<= 1) {
        int v = (t >= st) ? s[t - st] : 0;
        __syncthreads();
        s[t] += v;
        __syncthreads();
    }
    int excl = (t == 0) ? 0 : s[t - 1];
    if (t < nbuck) { bucket_base[t] = excl; bucket_cursor[t] = excl; }
    if (t == 0) bucket_base[nbuck] = E;
}

// ---- pass B: partition edges by bucket; packed value = src | (dst&1023)<<17.
__global__ void k_part(const int* __restrict__ idx, int* __restrict__ bucket_cursor,
                       int* __restrict__ edge_part, int E) {
    __shared__ int h[MAXBUCK];
    __shared__ int rbase[MAXBUCK];
    bool is64 = detect64(idx);
    for (int i = threadIdx.x; i < MAXBUCK; i += BLK) h[i] = 0;
    __syncthreads();
    int base = blockIdx.x * (BLK * EPT) + threadIdx.x;
    int dst[EPT], src[EPT];
#pragma unroll
    for (int k = 0; k < EPT; ++k) {
        int e = base + k * BLK;
        if (e < E) {
            dst[k] = is64 ? idx[2 * (E + e)] : idx[E + e];
            src[k] = is64 ? idx[2 * e] : idx[e];
            atomicAdd(&h[dst[k] >> BSHIFT], 1);
        } else {
            dst[k] = -1;
        }
    }
    __syncthreads();
    for (int i = threadIdx.x; i < MAXBUCK; i += BLK) {
        int c = h[i];
        rbase[i] = c ? atomicAdd(&bucket_cursor[i], c) : 0;
        h[i] = 0;
    }
    __syncthreads();
#pragma unroll
    for (int k = 0; k < EPT; ++k) {
        if (dst[k] >= 0) {
            int b = dst[k] >> BSHIFT;
            int r = atomicAdd(&h[b], 1);
            edge_part[rbase[b] + r] = src[k] | ((dst[k] & (NPB - 1)) << 17);
        }
    }
}

// ---- pass C: one workgroup per bucket; per-node count/scan/cursor in LDS;
// emits row_ptr, dinv, csr_src (random stores confined to this CU's ~64KB region).
__global__ void k_csr(const int* __restrict__ edge_part, const int* __restrict__ bucket_base,
                      int* __restrict__ row_ptr, float* __restrict__ dinv,
                      int* __restrict__ csr_src, int N, int E, int nbuck) {
    __shared__ int cnt[NPB];
    __shared__ int off[NPB];
    __shared__ int tsum[BLK];
    int b = blockIdx.x;
    int node0 = b << BSHIFT;
    int nn = min(NPB, N - node0);
    int ebeg = bucket_base[b], eend = bucket_base[b + 1];
    int t = threadIdx.x;
    for (int i = t; i < NPB; i += BLK) cnt[i] = 0;
    __syncthreads();
    for (int e = ebeg + t; e < eend; e += BLK)
        atomicAdd(&cnt[((unsigned)edge_part[e]) >> 17], 1);
    __syncthreads();
    int c0 = cnt[4 * t], c1 = cnt[4 * t + 1], c2 = cnt[4 * t + 2], c3 = cnt[4 * t + 3];
    tsum[t] = c0 + c1 + c2 + c3;
    __syncthreads();
    for (int st = 1; st < BLK; st <<= 1) {
        int v = (t >= st) ? tsum[t - st] : 0;
        __syncthreads();
        tsum[t] += v;
        __syncthreads();
    }
    int ex = (t == 0) ? 0 : tsum[t - 1];
    off[4 * t] = ex;
    off[4 * t + 1] = ex + c0;
    off[4 * t + 2] = ex + c0 + c1;
    off[4 * t + 3] = ex + c0 + c1 + c2;
    __syncthreads();
    for (int i = t; i < nn; i += BLK) {
        row_ptr[node0 + i] = ebeg + off[i];
        dinv[node0 + i] = rsqrtf((float)(cnt[i] + 1));  // +1 self-loop
    }
    if (b == nbuck - 1 && t == 0) row_ptr[N] = E;
    __syncthreads();
    for (int e = ebeg + t; e < eend; e += BLK) {
        int p = edge_part[e];
        int dlo = ((unsigned)p) >> 17;
        int r = atomicAdd(&off[dlo], 1);
        csr_src[ebeg + r] = p & 0x1FFFF;
    }
}

// ---- layer 1 GEMM (register-tiled): 64 rows x 64 cols per block.
// Thread (tx,ty), tx,ty in [0,16): rows {ty+16i}, cols {tx+16j} (strided ownership
// -> each wave's 4 ty / 16 tx values hit distinct LDS bank sets; <=2-way = free).
// 16 NAMED scalar accumulators (R6's arrays were sent to scratch: 700MB traffic).
__global__ __launch_bounds__(256) void k_gemm1(
        const float* __restrict__ x, const float* __restrict__ W1,
        const float* __restrict__ dinv, ushort_t* __restrict__ hs1, int N) {
    __shared__ float xs[64][68];     // 17.0 KB: one 64-wide K-chunk of the x tile
    __shared__ float wT[64][132];    // 33.8 KB: transposed W1 (full K=128)
    int t = threadIdx.x;
    int rbase = blockIdx.x * 64;
    // stage W1 transposed: wT[c][k] = W1[k][c]
    for (int i = t; i < 2048; i += BLK) {
        int k = i >> 4, c4 = i & 15;
        float4 w = ((const float4*)W1)[i];
        wT[4 * c4 + 0][k] = w.x; wT[4 * c4 + 1][k] = w.y;
        wT[4 * c4 + 2][k] = w.z; wT[4 * c4 + 3][k] = w.w;
    }
    int tx = t & 15, ty = t >> 4;
    float a00 = 0.f, a01 = 0.f, a02 = 0.f, a03 = 0.f;
    float a10 = 0.f, a11 = 0.f, a12 = 0.f, a13 = 0.f;
    float a20 = 0.f, a21 = 0.f, a22 = 0.f, a23 = 0.f;
    float a30 = 0.f, a31 = 0.f, a32 = 0.f, a33 = 0.f;
    const float4* xv = (const float4*)x;
    for (int kb = 0; kb < 128; kb += 64) {
        __syncthreads();             // covers wT staging on first pass, xs reuse after
        for (int i = t; i < 1024; i += BLK) {
            int r = i >> 4, c = i & 15;
            int rr = rbase + r; if (rr >= N) rr = N - 1;
            *(float4*)&xs[r][4 * c] = xv[(size_t)rr * 32 + (kb >> 2) + c];
        }
        __syncthreads();
#pragma unroll 4
        for (int k0 = 0; k0 < 64; k0 += 4) {
            float4 x0 = *(const float4*)&xs[ty][k0];
            float4 x1 = *(const float4*)&xs[ty + 16][k0];
            float4 x2 = *(const float4*)&xs[ty + 32][k0];
            float4 x3 = *(const float4*)&xs[ty + 48][k0];
            float4 w0 = *(const float4*)&wT[tx][kb + k0];
            float4 w1 = *(const float4*)&wT[tx + 16][kb + k0];
            float4 w2 = *(const float4*)&wT[tx + 32][kb + k0];
            float4 w3 = *(const float4*)&wT[tx + 48][kb + k0];
            DOT4(a00, x0, w0); DOT4(a01, x0, w1); DOT4(a02, x0, w2); DOT4(a03, x0, w3);
            DOT4(a10, x1, w0); DOT4(a11, x1, w1); DOT4(a12, x1, w2); DOT4(a13, x1, w3);
            DOT4(a20, x2, w0); DOT4(a21, x2, w1); DOT4(a22, x2, w2); DOT4(a23, x2, w3);
            DOT4(a30, x3, w0); DOT4(a31, x3, w1); DOT4(a32, x3, w2); DOT4(a33, x3, w3);
        }
    }
    // epilogue: scale by dinv, bounce through LDS (strided cols -> coalesced stores)
    __syncthreads();
    {
        int r0 = rbase + ty;      float s0 = dinv[r0 < N ? r0 : N - 1];
        int r1 = rbase + ty + 16; float s1 = dinv[r1 < N ? r1 : N - 1];
        int r2 = rbase + ty + 32; float s2 = dinv[r2 < N ? r2 : N - 1];
        int r3 = rbase + ty + 48; float s3 = dinv[r3 < N ? r3 : N - 1];
        xs[ty][tx]      = a00 * s0; xs[ty][tx + 16]      = a01 * s0;
        xs[ty][tx + 32] = a02 * s0; xs[ty][tx + 48]      = a03 * s0;
        xs[ty + 16][tx]      = a10 * s1; xs[ty + 16][tx + 16] = a11 * s1;
        xs[ty + 16][tx + 32] = a12 * s1; xs[ty + 16][tx + 48] = a13 * s1;
        xs[ty + 32][tx]      = a20 * s2; xs[ty + 32][tx + 16] = a21 * s2;
        xs[ty + 32][tx + 32] = a22 * s2; xs[ty + 32][tx + 48] = a23 * s2;
        xs[ty + 48][tx]      = a30 * s3; xs[ty + 48][tx + 16] = a31 * s3;
        xs[ty + 48][tx + 32] = a32 * s3; xs[ty + 48][tx + 48] = a33 * s3;
    }
    __syncthreads();
    for (int i = t; i < 1024; i += BLK) {
        int r = i >> 4, c4 = i & 15;
        int rr = rbase + r;
        if (rr < N) {
            float4 v = *(const float4*)&xs[r][4 * c4];
            uint2 o;
            o.x = f2bf(v.x) | (f2bf(v.y) << 16);
            o.y = f2bf(v.z) | (f2bf(v.w) << 16);
            *(uint2*)&hs1[(size_t)rr * 64 + 4 * c4] = o;
        }
    }
}

// ---- layer 1 aggregation: one wave per node; 8 groups x 8 lanes, each lane a
// uint4 (8 bf16); unroll 2 -> 16 independent 128B row gathers in flight.
__global__ void k_agg1(const uint_t* __restrict__ hs1, const int* __restrict__ row_ptr,
                       const int* __restrict__ csr_src, const float* __restrict__ dinv,
                       const float* __restrict__ b1, float* __restrict__ a1, int N) {
    int node = (blockIdx.x * blockDim.x + threadIdx.x) >> 6;
    if (node >= N) return;
    int lane = threadIdx.x & 63;
    int g = lane >> 3;   // edge slot 0..7
    int c = lane & 7;    // uint4 column: features [8c, 8c+8)
    const uint4* H = (const uint4*)hs1;  // row i at H[i*8 + c]

    float acc[8] = {0.f, 0.f, 0.f, 0.f, 0.f, 0.f, 0.f, 0.f};
    if (g == 0) bfacc(acc, H[(size_t)node * 8 + c]);  // self-loop (pre-scaled)

    int beg = row_ptr[node], end = row_ptr[node + 1];
    int e = beg + g;
    for (; e + 8 < end; e += 16) {
        int j0 = csr_src[e];
        int j1 = csr_src[e + 8];
        uint4 v0 = H[(size_t)j0 * 8 + c];
        uint4 v1 = H[(size_t)j1 * 8 + c];
        bfacc(acc, v0);
        bfacc(acc, v1);
    }
    if (e < end) {
        int j = csr_src[e];
        bfacc(acc, H[(size_t)j * 8 + c]);
    }
#pragma unroll
    for (int m = 8; m <= 32; m <<= 1)
#pragma unroll
        for (int i = 0; i < 8; ++i) acc[i] += __shfl_xor(acc[i], m, 64);
    if (g == 0) {
        float s = dinv[node];
        const float4* B = (const float4*)b1;
        float4 bv0 = B[2 * c], bv1 = B[2 * c + 1];
        float4 o0, o1;
        o0.x = fmaxf(fmaf(acc[0], s, bv0.x), 0.f);
        o0.y = fmaxf(fmaf(acc[1], s, bv0.y), 0.f);
        o0.z = fmaxf(fmaf(acc[2], s, bv0.z), 0.f);
        o0.w = fmaxf(fmaf(acc[3], s, bv0.w), 0.f);
        o1.x = fmaxf(fmaf(acc[4], s, bv1.x), 0.f);
        o1.y = fmaxf(fmaf(acc[5], s, bv1.y), 0.f);
        o1.z = fmaxf(fmaf(acc[6], s, bv1.z), 0.f);
        o1.w = fmaxf(fmaf(acc[7], s, bv1.w), 0.f);
        float4* A = (float4*)a1;
        A[(size_t)node * 16 + 2 * c] = o0;
        A[(size_t)node * 16 + 2 * c + 1] = o1;
    }
}

// ---- layer 2 GEMM (register-tiled): 128 rows x 32 cols per block.
// Thread (tx,ty), tx in [0,8), ty in [0,32): rows {ty+32i}, cols {tx+8j}.
__global__ __launch_bounds__(256) void k_gemm2(
        const float* __restrict__ a1, const float* __restrict__ W2,
        const float* __restrict__ dinv, ushort_t* __restrict__ hs2, int N) {
    __shared__ float as[128][68];    // 34.8 KB
    __shared__ float wT[32][68];     // 8.7 KB: transposed W2
    int t = threadIdx.x;
    int rbase = blockIdx.x * 128;
    for (int i = t; i < 512; i += BLK) {
        int k = i >> 3, c4 = i & 7;
        float4 w = ((const float4*)W2)[i];
        wT[4 * c4 + 0][k] = w.x; wT[4 * c4 + 1][k] = w.y;
        wT[4 * c4 + 2][k] = w.z; wT[4 * c4 + 3][k] = w.w;
    }
    const float4* av = (const float4*)a1;
    for (int i = t; i < 2048; i += BLK) {
        int r = i >> 4, c = i & 15;
        int rr = rbase + r; if (rr >= N) rr = N - 1;
        *(float4*)&as[r][4 * c] = av[(size_t)rr * 16 + c];
    }
    __syncthreads();
    int tx = t & 7, ty = t >> 3;
    float a00 = 0.f, a01 = 0.f, a02 = 0.f, a03 = 0.f;
    float a10 = 0.f, a11 = 0.f, a12 = 0.f, a13 = 0.f;
    float a20 = 0.f, a21 = 0.f, a22 = 0.f, a23 = 0.f;
    float a30 = 0.f, a31 = 0.f, a32 = 0.f, a33 = 0.f;
#pragma unroll 4
    for (int k0 = 0; k0 < 64; k0 += 4) {
        float4 x0 = *(const float4*)&as[ty][k0];
        float4 x1 = *(const float4*)&as[ty + 32][k0];
        float4 x2 = *(const float4*)&as[ty + 64][k0];
        float4 x3 = *(const float4*)&as[ty + 96][k0];
        float4 w0 = *(const float4*)&wT[tx][k0];
        float4 w1 = *(const float4*)&wT[tx + 8][k0];
        float4 w2 = *(const float4*)&wT[tx + 16][k0];
        float4 w3 = *(const float4*)&wT[tx + 24][k0];
        DOT4(a00, x0, w0); DOT4(a01, x0, w1); DOT4(a02, x0, w2); DOT4(a03, x0, w3);
        DOT4(a10, x1, w0); DOT4(a11, x1, w1); DOT4(a12, x1, w2); DOT4(a13, x1, w3);
        DOT4(a20, x2, w0); DOT4(a21, x2, w1); DOT4(a22, x2, w2); DOT4(a23, x2, w3);
        DOT4(a30, x3, w0); DOT4(a31, x3, w1); DOT4(a32, x3, w2); DOT4(a33, x3, w3);
    }
    // epilogue via LDS bounce
    __syncthreads();
    {
        int r0 = rbase + ty;      float s0 = dinv[r0 < N ? r0 : N - 1];
        int r1 = rbase + ty + 32; float s1 = dinv[r1 < N ? r1 : N - 1];
        int r2 = rbase + ty + 64; float s2 = dinv[r2 < N ? r2 : N - 1];
        int r3 = rbase + ty + 96; float s3 = dinv[r3 < N ? r3 : N - 1];
        as[ty][tx]      = a00 * s0; as[ty][tx + 8]       = a01 * s0;
        as[ty][tx + 16] = a02 * s0; as[ty][tx + 24]      = a03 * s0;
        as[ty + 32][tx]      = a10 * s1; as[ty + 32][tx + 8]  = a11 * s1;
        as[ty + 32][tx + 16] = a12 * s1; as[ty + 32][tx + 24] = a13 * s1;
        as[ty + 64][tx]      = a20 * s2; as[ty + 64][tx + 8]  = a21 * s2;
        as[ty + 64][tx + 16] = a22 * s2; as[ty + 64][tx + 24] = a23 * s2;
        as[ty + 96][tx]      = a30 * s3; as[ty + 96][tx + 8]  = a31 * s3;
        as[ty + 96][tx + 16] = a32 * s3; as[ty + 96][tx + 24] = a33 * s3;
    }
    __syncthreads();
    for (int i = t; i < 1024; i += BLK) {
        int r = i >> 3, c4 = i & 7;
        int rr = rbase + r;
        if (rr < N) {
            float4 v = *(const float4*)&as[r][4 * c4];
            uint2 o;
            o.x = f2bf(v.x) | (f2bf(v.y) << 16);
            o.y = f2bf(v.z) | (f2bf(v.w) << 16);
            *(uint2*)&hs2[(size_t)rr * 32 + 4 * c4] = o;
        }
    }
}

// ---- layer 2 aggregation: 16 groups x 4 lanes (64B bf16 rows), unroll 2
// -> up to 32 independent row gathers in flight.
__global__ void k_agg2(const uint_t* __restrict__ hs2, const int* __restrict__ row_ptr,
                       const int* __restrict__ csr_src, const float* __restrict__ dinv,
                       const float* __restrict__ b2, float* __restrict__ out, int N) {
    int node = (blockIdx.x * blockDim.x + threadIdx.x) >> 6;
    if (node >= N) return;
    int lane = threadIdx.x & 63;
    int g = lane >> 2;   // edge slot 0..15
    int c = lane & 3;    // uint4 column: features [8c, 8c+8)
    const uint4* H = (const uint4*)hs2;  // row i at H[i*4 + c]

    float acc[8] = {0.f, 0.f, 0.f, 0.f, 0.f, 0.f, 0.f, 0.f};
    if (g == 0) bfacc(acc, H[(size_t)node * 4 + c]);  // self-loop

    int beg = row_ptr[node], end = row_ptr[node + 1];
    int e = beg + g;
    for (; e + 16 < end; e += 32) {
        int j0 = csr_src[e];
        int j1 = csr_src[e + 16];
        uint4 v0 = H[(size_t)j0 * 4 + c];
        uint4 v1 = H[(size_t)j1 * 4 + c];
        bfacc(acc, v0);
        bfacc(acc, v1);
    }
    if (e < end) {
        int j = csr_src[e];
        bfacc(acc, H[(size_t)j * 4 + c]);
    }
#pragma unroll
    for (int m = 4; m <= 32; m <<= 1)
#pragma unroll
        for (int i = 0; i < 8; ++i) acc[i] += __shfl_xor(acc[i], m, 64);
    if (g == 0) {
        float s = dinv[node];
        const float4* B = (const float4*)b2;
        float4 bv0 = B[2 * c], bv1 = B[2 * c + 1];
        float4 o0, o1;
        o0.x = fmaf(acc[0], s, bv0.x);
        o0.y = fmaf(acc[1], s, bv0.y);
        o0.z = fmaf(acc[2], s, bv0.z);
        o0.w = fmaf(acc[3], s, bv0.w);
        o1.x = fmaf(acc[4], s, bv1.x);
        o1.y = fmaf(acc[5], s, bv1.y);
        o1.z = fmaf(acc[6], s, bv1.z);
        o1.w = fmaf(acc[7], s, bv1.w);
        float4* O = (float4*)out;
        O[(size_t)node * 8 + 2 * c] = o0;
        O[(size_t)node * 8 + 2 * c + 1] = o1;
    }
}

extern "C" void kernel_launch(void* const* d_in, const int* in_sizes, int n_in,
                              void* d_out, int out_size, void* d_ws, size_t ws_size,
                              hipStream_t stream) {
    const float* x  = (const float*)d_in[0];
    const int*   idx = (const int*)d_in[1];
    const float* W1 = (const float*)d_in[2];
    const float* b1 = (const float*)d_in[3];
    const float* W2 = (const float*)d_in[4];
    const float* b2 = (const float*)d_in[5];
    float* out = (float*)d_out;

    const int N = in_sizes[0] / 128;   // 100000 (< 2^17, required by packing)
    const int E = in_sizes[1] / 2;     // 1600000
    const int nbuck = (N + NPB - 1) >> BSHIFT;   // 98 (<= MAXBUCK)

    // workspace layout (256B aligned)
    char* ws = (char*)d_ws;
    size_t off = 0;
    auto alloc = [&](size_t bytes) -> char* {
        char* p = ws + off;
        off = (off + bytes + 255) & ~(size_t)255;
        return p;
    };
    float* dinv     = (float*)alloc((size_t)N * 4);
    int*   row_ptr  = (int*)alloc((size_t)(N + 1) * 4);
    int*   bcounts  = (int*)alloc(MAXBUCK * 4);
    int*   bbase    = (int*)alloc((MAXBUCK + 1) * 4);
    int*   bcursor  = (int*)alloc(MAXBUCK * 4);
    int*   csr_src  = (int*)alloc((size_t)E * 4);
    ushort_t* hs1   = (ushort_t*)alloc((size_t)N * 64 * 2);  // bf16
    float* a1       = (float*)alloc((size_t)N * 64 * 4);
    ushort_t* hs2   = hs1;               // reuse: hs1 dead after k_agg1
    int*   edge_part = (int*)hs1;        // reuse: hs1 written only at k_gemm1

    const int ebk = (E + BLK * EPT - 1) / (BLK * EPT);  // 782

    hipMemsetAsync(bcounts, 0, MAXBUCK * 4, stream);
    k_hist<<<ebk, BLK, 0, stream>>>(idx, bcounts, E);
    k_bscan<<<1, MAXBUCK, 0, stream>>>(bcounts, bbase, bcursor, nbuck, E);
    k_part<<<ebk, BLK, 0, stream>>>(idx, bcursor, edge_part, E);
    k_csr<<<nbuck, BLK, 0, stream>>>(edge_part, bbase, row_ptr, dinv, csr_src, N, E, nbuck);

    k_gemm1<<<(N + 63) / 64, 256, 0, stream>>>(x, W1, dinv, hs1, N);
    k_agg1<<<(N + 3) / 4, 256, 0, stream>>>((const uint_t*)hs1, row_ptr, csr_src, dinv, b1, a1, N);
    k_gemm2<<<(N + 127) / 128, 256, 0, stream>>>(a1, W2, dinv, hs2, N);
    k_agg2<<<(N + 3) / 4, 256, 0, stream>>>((const uint_t*)hs2, row_ptr, csr_src, dinv, b2, out, N);
}

// Round 8
// 296.636 us; speedup vs baseline: 2.1991x; 1.0765x over previous
//
#include <hip/hip_runtime.h>

// GCN 2-layer: x[N,128] -> GCNConv(W1[128,64], b1) -> ReLU -> GCNConv(W2[64,32], b2)
// norm = dinv[src]*dinv[dst] factorized: pre-scale h by dinv, aggregate, post-scale.
// CSR build via bucketed multisplit (R4). bf16 intermediates (R5).
// R8: GEMMs moved to MFMA bf16 (mfma_f32_16x16x32_bf16, fp32 accumulate).
// R7's fp32-VALU GEMM was LDS/VALU-bound (49.6us, 3.1M conflict cy, 22% occ);
// MFMA makes compute negligible -> gemm1 bound by reading x (~51MB ~ 10us).
// a1 stored bf16 (needed for gemm2-MFMA anyway): halves agg1 write + gemm2 read.

#define BLK 256
#define EPT 8            // edges/thread in hist & part
#define BSHIFT 10        // nodes per bucket
#define NPB 1024         // 1 << BSHIFT
#define MAXBUCK 128      // >= nbuck = ceil(N / NPB); N=100K -> 98

typedef unsigned int uint_t;
typedef unsigned short ushort_t;
typedef __attribute__((ext_vector_type(8))) short bf16x8;   // MFMA A/B frag (4 VGPR)
typedef __attribute__((ext_vector_type(4))) float f32x4;    // MFMA C/D frag

__device__ __forceinline__ uint_t f2bf(float x) {   // RNE float->bf16 (low 16)
    union { float f; uint_t u; } un; un.f = x;
    uint_t u = un.u;
    return (u + 0x7fffu + ((u >> 16) & 1u)) >> 16;
}
__device__ __forceinline__ void bfacc(float* a, uint4 v) {  // 8 bf16 += into fp32
    a[0] += __uint_as_float(v.x << 16);
    a[1] += __uint_as_float(v.x & 0xffff0000u);
    a[2] += __uint_as_float(v.y << 16);
    a[3] += __uint_as_float(v.y & 0xffff0000u);
    a[4] += __uint_as_float(v.z << 16);
    a[5] += __uint_as_float(v.z & 0xffff0000u);
    a[6] += __uint_as_float(v.w << 16);
    a[7] += __uint_as_float(v.w & 0xffff0000u);
}

// int64-layout detection (wave-uniform, L2-hot): odd 32-bit words of the first
// 16 index values are all zero iff indices are little-endian int64.
__device__ __forceinline__ bool detect64(const int* __restrict__ idx) {
    int z = 0;
#pragma unroll
    for (int i = 1; i < 32; i += 2) z |= idx[i];
    return z == 0;
}

// ---- pass A: per-bucket histogram (LDS-accumulated, 1 global atomic/bucket/block)
__global__ void k_hist(const int* __restrict__ idx, int* __restrict__ bucket_counts,
                       int E) {
    __shared__ int h[MAXBUCK];
    bool is64 = detect64(idx);
    for (int i = threadIdx.x; i < MAXBUCK; i += BLK) h[i] = 0;
    __syncthreads();
    int base = blockIdx.x * (BLK * EPT) + threadIdx.x;
#pragma unroll
    for (int k = 0; k < EPT; ++k) {
        int e = base + k * BLK;
        if (e < E) {
            int d = is64 ? idx[2 * (E + e)] : idx[E + e];
            atomicAdd(&h[d >> BSHIFT], 1);
        }
    }
    __syncthreads();
    for (int i = threadIdx.x; i < MAXBUCK; i += BLK)
        if (h[i]) atomicAdd(&bucket_counts[i], h[i]);
}

// ---- scan bucket counts -> bucket_base[nbuck+1], init cursors
__global__ void k_bscan(const int* __restrict__ bucket_counts, int* __restrict__ bucket_base,
                        int* __restrict__ bucket_cursor, int nbuck, int E) {
    __shared__ int s[MAXBUCK];
    int t = threadIdx.x;  // MAXBUCK threads
    s[t] = (t < nbuck) ? bucket_counts[t] : 0;
    __syncthreads();
    for (int st = 1; st < MAXBUCK; st <<= 1) {
        int v = (t >= st) ? s[t - st] : 0;
        __syncthreads();
        s[t] += v;
        __syncthreads();
    }
    int excl = (t == 0) ? 0 : s[t - 1];
    if (t < nbuck) { bucket_base[t] = excl; bucket_cursor[t] = excl; }
    if (t == 0) bucket_base[nbuck] = E;
}

// ---- pass B: partition edges by bucket; packed value = src | (dst&1023)<<17.
__global__ void k_part(const int* __restrict__ idx, int* __restrict__ bucket_cursor,
                       int* __restrict__ edge_part, int E) {
    __shared__ int h[MAXBUCK];
    __shared__ int rbase[MAXBUCK];
    bool is64 = detect64(idx);
    for (int i = threadIdx.x; i < MAXBUCK; i += BLK) h[i] = 0;
    __syncthreads();
    int base = blockIdx.x * (BLK * EPT) + threadIdx.x;
    int dst[EPT], src[EPT];
#pragma unroll
    for (int k = 0; k < EPT; ++k) {
        int e = base + k * BLK;
        if (e < E) {
            dst[k] = is64 ? idx[2 * (E + e)] : idx[E + e];
            src[k] = is64 ? idx[2 * e] : idx[e];
            atomicAdd(&h[dst[k] >> BSHIFT], 1);
        } else {
            dst[k] = -1;
        }
    }
    __syncthreads();
    for (int i = threadIdx.x; i < MAXBUCK; i += BLK) {
        int c = h[i];
        rbase[i] = c ? atomicAdd(&bucket_cursor[i], c) : 0;
        h[i] = 0;
    }
    __syncthreads();
#pragma unroll
    for (int k = 0; k < EPT; ++k) {
        if (dst[k] >= 0) {
            int b = dst[k] >> BSHIFT;
            int r = atomicAdd(&h[b], 1);
            edge_part[rbase[b] + r] = src[k] | ((dst[k] & (NPB - 1)) << 17);
        }
    }
}

// ---- pass C: one workgroup per bucket; per-node count/scan/cursor in LDS;
// emits row_ptr, dinv, csr_src (random stores confined to this CU's ~64KB region).
__global__ void k_csr(const int* __restrict__ edge_part, const int* __restrict__ bucket_base,
                      int* __restrict__ row_ptr, float* __restrict__ dinv,
                      int* __restrict__ csr_src, int N, int E, int nbuck) {
    __shared__ int cnt[NPB];
    __shared__ int off[NPB];
    __shared__ int tsum[BLK];
    int b = blockIdx.x;
    int node0 = b << BSHIFT;
    int nn = min(NPB, N - node0);
    int ebeg = bucket_base[b], eend = bucket_base[b + 1];
    int t = threadIdx.x;
    for (int i = t; i < NPB; i += BLK) cnt[i] = 0;
    __syncthreads();
    for (int e = ebeg + t; e < eend; e += BLK)
        atomicAdd(&cnt[((unsigned)edge_part[e]) >> 17], 1);
    __syncthreads();
    int c0 = cnt[4 * t], c1 = cnt[4 * t + 1], c2 = cnt[4 * t + 2], c3 = cnt[4 * t + 3];
    tsum[t] = c0 + c1 + c2 + c3;
    __syncthreads();
    for (int st = 1; st < BLK; st <<= 1) {
        int v = (t >= st) ? tsum[t - st] : 0;
        __syncthreads();
        tsum[t] += v;
        __syncthreads();
    }
    int ex = (t == 0) ? 0 : tsum[t - 1];
    off[4 * t] = ex;
    off[4 * t + 1] = ex + c0;
    off[4 * t + 2] = ex + c0 + c1;
    off[4 * t + 3] = ex + c0 + c1 + c2;
    __syncthreads();
    for (int i = t; i < nn; i += BLK) {
        row_ptr[node0 + i] = ebeg + off[i];
        dinv[node0 + i] = rsqrtf((float)(cnt[i] + 1));  // +1 self-loop
    }
    if (b == nbuck - 1 && t == 0) row_ptr[N] = E;
    __syncthreads();
    for (int e = ebeg + t; e < eend; e += BLK) {
        int p = edge_part[e];
        int dlo = ((unsigned)p) >> 17;
        int r = atomicAdd(&off[dlo], 1);
        csr_src[ebeg + r] = p & 0x1FFFF;
    }
}

// ---- layer 1 GEMM (MFMA bf16): 64 rows x 64 cols per block, 4 waves.
// Wave w: rows [16w,16w+16), 4 col-tiles. K=128 = 4 MFMA k-steps.
// A frag: lane holds xb[16w + (l&15)][quad*8..+8]; B frag: wb[(l&15)+16c][quad*8..+8].
// LDS rows padded to 136 bf16 (272B = 68 dwords, 68 mod 32 = 4) -> frag reads <=2-way.
__global__ __launch_bounds__(256) void k_gemm1(
        const float* __restrict__ x, const float* __restrict__ W1,
        const float* __restrict__ dinv, ushort_t* __restrict__ hs1, int N) {
    __shared__ ushort_t xb[64][136];   // 17.4 KB: x tile, bf16
    __shared__ ushort_t wb[64][136];   // 17.4 KB: W1 transposed (wb[n][k]), bf16
    int t = threadIdx.x;
    int rbase = blockIdx.x * 64;
    // stage W1 -> wb[n][k]: thread i: k=i>>4, n4=i&15 (W1 row = 16 float4)
    for (int i = t; i < 2048; i += BLK) {
        int k = i >> 4, n4 = i & 15;
        float4 w = ((const float4*)W1)[i];
        wb[4 * n4 + 0][k] = (ushort_t)f2bf(w.x);
        wb[4 * n4 + 1][k] = (ushort_t)f2bf(w.y);
        wb[4 * n4 + 2][k] = (ushort_t)f2bf(w.z);
        wb[4 * n4 + 3][k] = (ushort_t)f2bf(w.w);
    }
    // stage x -> xb (convert fp32->bf16): thread i: r=i>>5, c4=i&31 (x row = 32 float4)
    for (int i = t; i < 2048; i += BLK) {
        int r = i >> 5, c4 = i & 31;
        int rr = rbase + r; if (rr >= N) rr = N - 1;
        float4 v = ((const float4*)x)[(size_t)rr * 32 + c4];
        uint2 p;
        p.x = f2bf(v.x) | (f2bf(v.y) << 16);
        p.y = f2bf(v.z) | (f2bf(v.w) << 16);
        *(uint2*)&xb[r][4 * c4] = p;
    }
    __syncthreads();
    int w = t >> 6, l = t & 63;
    int lane16 = l & 15, quad = l >> 4;
    int mrow = 16 * w + lane16;
    f32x4 acc0 = {0.f, 0.f, 0.f, 0.f}, acc1 = {0.f, 0.f, 0.f, 0.f};
    f32x4 acc2 = {0.f, 0.f, 0.f, 0.f}, acc3 = {0.f, 0.f, 0.f, 0.f};
#pragma unroll
    for (int kk = 0; kk < 4; ++kk) {
        int k0 = kk * 32 + quad * 8;
        bf16x8 a  = *(const bf16x8*)&xb[mrow][k0];
        bf16x8 b0 = *(const bf16x8*)&wb[lane16][k0];
        bf16x8 b1 = *(const bf16x8*)&wb[lane16 + 16][k0];
        bf16x8 b2 = *(const bf16x8*)&wb[lane16 + 32][k0];
        bf16x8 b3 = *(const bf16x8*)&wb[lane16 + 48][k0];
        acc0 = __builtin_amdgcn_mfma_f32_16x16x32_bf16(a, b0, acc0, 0, 0, 0);
        acc1 = __builtin_amdgcn_mfma_f32_16x16x32_bf16(a, b1, acc1, 0, 0, 0);
        acc2 = __builtin_amdgcn_mfma_f32_16x16x32_bf16(a, b2, acc2, 0, 0, 0);
        acc3 = __builtin_amdgcn_mfma_f32_16x16x32_bf16(a, b3, acc3, 0, 0, 0);
    }
    // epilogue: D row = 16w + quad*4 + reg, col = 16c + lane16; scale dinv, bf16,
    // scatter to xb then coalesced uint4 store.
    __syncthreads();
    int orow = 16 * w + quad * 4;
    float d0 = dinv[min(rbase + orow + 0, N - 1)];
    float d1 = dinv[min(rbase + orow + 1, N - 1)];
    float d2 = dinv[min(rbase + orow + 2, N - 1)];
    float d3 = dinv[min(rbase + orow + 3, N - 1)];
    xb[orow + 0][lane16]      = (ushort_t)f2bf(acc0.x * d0);
    xb[orow + 1][lane16]      = (ushort_t)f2bf(acc0.y * d1);
    xb[orow + 2][lane16]      = (ushort_t)f2bf(acc0.z * d2);
    xb[orow + 3][lane16]      = (ushort_t)f2bf(acc0.w * d3);
    xb[orow + 0][lane16 + 16] = (ushort_t)f2bf(acc1.x * d0);
    xb[orow + 1][lane16 + 16] = (ushort_t)f2bf(acc1.y * d1);
    xb[orow + 2][lane16 + 16] = (ushort_t)f2bf(acc1.z * d2);
    xb[orow + 3][lane16 + 16] = (ushort_t)f2bf(acc1.w * d3);
    xb[orow + 0][lane16 + 32] = (ushort_t)f2bf(acc2.x * d0);
    xb[orow + 1][lane16 + 32] = (ushort_t)f2bf(acc2.y * d1);
    xb[orow + 2][lane16 + 32] = (ushort_t)f2bf(acc2.z * d2);
    xb[orow + 3][lane16 + 32] = (ushort_t)f2bf(acc2.w * d3);
    xb[orow + 0][lane16 + 48] = (ushort_t)f2bf(acc3.x * d0);
    xb[orow + 1][lane16 + 48] = (ushort_t)f2bf(acc3.y * d1);
    xb[orow + 2][lane16 + 48] = (ushort_t)f2bf(acc3.z * d2);
    xb[orow + 3][lane16 + 48] = (ushort_t)f2bf(acc3.w * d3);
    __syncthreads();
    for (int i = t; i < 512; i += BLK) {    // 64 rows x 8 uint4 (row = 64 bf16)
        int r = i >> 3, c8 = i & 7;
        int rr = rbase + r;
        if (rr < N) {
            uint4 v = *(const uint4*)&xb[r][8 * c8];
            *(uint4*)&hs1[(size_t)rr * 64 + 8 * c8] = v;
        }
    }
}

// ---- layer 1 aggregation: one wave per node; 8 groups x 8 lanes, each lane a
// uint4 (8 bf16); unroll 2 -> 16 independent 128B row gathers in flight.
// Output a1 now bf16 (feeds gemm2-MFMA; halves write traffic).
__global__ void k_agg1(const uint_t* __restrict__ hs1, const int* __restrict__ row_ptr,
                       const int* __restrict__ csr_src, const float* __restrict__ dinv,
                       const float* __restrict__ b1, ushort_t* __restrict__ a1b, int N) {
    int node = (blockIdx.x * blockDim.x + threadIdx.x) >> 6;
    if (node >= N) return;
    int lane = threadIdx.x & 63;
    int g = lane >> 3;   // edge slot 0..7
    int c = lane & 7;    // uint4 column: features [8c, 8c+8)
    const uint4* H = (const uint4*)hs1;  // row i at H[i*8 + c]

    float acc[8] = {0.f, 0.f, 0.f, 0.f, 0.f, 0.f, 0.f, 0.f};
    if (g == 0) bfacc(acc, H[(size_t)node * 8 + c]);  // self-loop (pre-scaled)

    int beg = row_ptr[node], end = row_ptr[node + 1];
    int e = beg + g;
    for (; e + 8 < end; e += 16) {
        int j0 = csr_src[e];
        int j1 = csr_src[e + 8];
        uint4 v0 = H[(size_t)j0 * 8 + c];
        uint4 v1 = H[(size_t)j1 * 8 + c];
        bfacc(acc, v0);
        bfacc(acc, v1);
    }
    if (e < end) {
        int j = csr_src[e];
        bfacc(acc, H[(size_t)j * 8 + c]);
    }
#pragma unroll
    for (int m = 8; m <= 32; m <<= 1)
#pragma unroll
        for (int i = 0; i < 8; ++i) acc[i] += __shfl_xor(acc[i], m, 64);
    if (g == 0) {
        float s = dinv[node];
        const float4* B = (const float4*)b1;
        float4 bv0 = B[2 * c], bv1 = B[2 * c + 1];
        float o0 = fmaxf(fmaf(acc[0], s, bv0.x), 0.f);
        float o1 = fmaxf(fmaf(acc[1], s, bv0.y), 0.f);
        float o2 = fmaxf(fmaf(acc[2], s, bv0.z), 0.f);
        float o3 = fmaxf(fmaf(acc[3], s, bv0.w), 0.f);
        float o4 = fmaxf(fmaf(acc[4], s, bv1.x), 0.f);
        float o5 = fmaxf(fmaf(acc[5], s, bv1.y), 0.f);
        float o6 = fmaxf(fmaf(acc[6], s, bv1.z), 0.f);
        float o7 = fmaxf(fmaf(acc[7], s, bv1.w), 0.f);
        uint4 o;
        o.x = f2bf(o0) | (f2bf(o1) << 16);
        o.y = f2bf(o2) | (f2bf(o3) << 16);
        o.z = f2bf(o4) | (f2bf(o5) << 16);
        o.w = f2bf(o6) | (f2bf(o7) << 16);
        ((uint4*)a1b)[(size_t)node * 8 + c] = o;
    }
}

// ---- layer 2 GEMM (MFMA bf16): 64 rows x 32 cols per block, 4 waves.
// Input a1b bf16 [N][64]; K=64 = 2 MFMA k-steps, 2 col-tiles.
__global__ __launch_bounds__(256) void k_gemm2(
        const ushort_t* __restrict__ a1b, const float* __restrict__ W2,
        const float* __restrict__ dinv, ushort_t* __restrict__ hs2, int N) {
    __shared__ ushort_t ab[64][72];    // 9.2 KB (row stride 144B = 36 dwords -> 2-way max)
    __shared__ ushort_t wb[32][72];    // 4.6 KB: W2 transposed, bf16
    int t = threadIdx.x;
    int rbase = blockIdx.x * 64;
    // stage W2 -> wb[n][k]: thread i: k=i>>3, n4=i&7 (W2 row = 8 float4)
    for (int i = t; i < 512; i += BLK) {
        int k = i >> 3, n4 = i & 7;
        float4 w = ((const float4*)W2)[i];
        wb[4 * n4 + 0][k] = (ushort_t)f2bf(w.x);
        wb[4 * n4 + 1][k] = (ushort_t)f2bf(w.y);
        wb[4 * n4 + 2][k] = (ushort_t)f2bf(w.z);
        wb[4 * n4 + 3][k] = (ushort_t)f2bf(w.w);
    }
    // stage a1b tile (already bf16): 64 rows x 8 uint4
    for (int i = t; i < 512; i += BLK) {
        int r = i >> 3, c8 = i & 7;
        int rr = rbase + r; if (rr >= N) rr = N - 1;
        uint4 v = ((const uint4*)a1b)[(size_t)rr * 8 + c8];
        *(uint4*)&ab[r][8 * c8] = v;
    }
    __syncthreads();
    int w = t >> 6, l = t & 63;
    int lane16 = l & 15, quad = l >> 4;
    int mrow = 16 * w + lane16;
    f32x4 acc0 = {0.f, 0.f, 0.f, 0.f}, acc1 = {0.f, 0.f, 0.f, 0.f};
#pragma unroll
    for (int kk = 0; kk < 2; ++kk) {
        int k0 = kk * 32 + quad * 8;
        bf16x8 a  = *(const bf16x8*)&ab[mrow][k0];
        bf16x8 b0 = *(const bf16x8*)&wb[lane16][k0];
        bf16x8 b1 = *(const bf16x8*)&wb[lane16 + 16][k0];
        acc0 = __builtin_amdgcn_mfma_f32_16x16x32_bf16(a, b0, acc0, 0, 0, 0);
        acc1 = __builtin_amdgcn_mfma_f32_16x16x32_bf16(a, b1, acc1, 0, 0, 0);
    }
    __syncthreads();
    int orow = 16 * w + quad * 4;
    float d0 = dinv[min(rbase + orow + 0, N - 1)];
    float d1 = dinv[min(rbase + orow + 1, N - 1)];
    float d2 = dinv[min(rbase + orow + 2, N - 1)];
    float d3 = dinv[min(rbase + orow + 3, N - 1)];
    ab[orow + 0][lane16]      = (ushort_t)f2bf(acc0.x * d0);
    ab[orow + 1][lane16]      = (ushort_t)f2bf(acc0.y * d1);
    ab[orow + 2][lane16]      = (ushort_t)f2bf(acc0.z * d2);
    ab[orow + 3][lane16]      = (ushort_t)f2bf(acc0.w * d3);
    ab[orow + 0][lane16 + 16] = (ushort_t)f2bf(acc1.x * d0);
    ab[orow + 1][lane16 + 16] = (ushort_t)f2bf(acc1.y * d1);
    ab[orow + 2][lane16 + 16] = (ushort_t)f2bf(acc1.z * d2);
    ab[orow + 3][lane16 + 16] = (ushort_t)f2bf(acc1.w * d3);
    __syncthreads();
    for (int i = t; i < 256; i += BLK) {    // 64 rows x 4 uint4 (row = 32 bf16)
        int r = i >> 2, c4 = i & 3;
        int rr = rbase + r;
        if (rr < N) {
            uint4 v = *(const uint4*)&ab[r][8 * c4];
            *(uint4*)&hs2[(size_t)rr * 32 + 8 * c4] = v;
        }
    }
}

// ---- layer 2 aggregation: 16 groups x 4 lanes (64B bf16 rows), unroll 2
// -> up to 32 independent row gathers in flight.
__global__ void k_agg2(const uint_t* __restrict__ hs2, const int* __restrict__ row_ptr,
                       const int* __restrict__ csr_src, const float* __restrict__ dinv,
                       const float* __restrict__ b2, float* __restrict__ out, int N) {
    int node = (blockIdx.x * blockDim.x + threadIdx.x) >> 6;
    if (node >= N) return;
    int lane = threadIdx.x & 63;
    int g = lane >> 2;   // edge slot 0..15
    int c = lane & 3;    // uint4 column: features [8c, 8c+8)
    const uint4* H = (const uint4*)hs2;  // row i at H[i*4 + c]

    float acc[8] = {0.f, 0.f, 0.f, 0.f, 0.f, 0.f, 0.f, 0.f};
    if (g == 0) bfacc(acc, H[(size_t)node * 4 + c]);  // self-loop

    int beg = row_ptr[node], end = row_ptr[node + 1];
    int e = beg + g;
    for (; e + 16 < end; e += 32) {
        int j0 = csr_src[e];
        int j1 = csr_src[e + 16];
        uint4 v0 = H[(size_t)j0 * 4 + c];
        uint4 v1 = H[(size_t)j1 * 4 + c];
        bfacc(acc, v0);
        bfacc(acc, v1);
    }
    if (e < end) {
        int j = csr_src[e];
        bfacc(acc, H[(size_t)j * 4 + c]);
    }
#pragma unroll
    for (int m = 4; m <= 32; m <<= 1)
#pragma unroll
        for (int i = 0; i < 8; ++i) acc[i] += __shfl_xor(acc[i], m, 64);
    if (g == 0) {
        float s = dinv[node];
        const float4* B = (const float4*)b2;
        float4 bv0 = B[2 * c], bv1 = B[2 * c + 1];
        float4 o0, o1;
        o0.x = fmaf(acc[0], s, bv0.x);
        o0.y = fmaf(acc[1], s, bv0.y);
        o0.z = fmaf(acc[2], s, bv0.z);
        o0.w = fmaf(acc[3], s, bv0.w);
        o1.x = fmaf(acc[4], s, bv1.x);
        o1.y = fmaf(acc[5], s, bv1.y);
        o1.z = fmaf(acc[6], s, bv1.z);
        o1.w = fmaf(acc[7], s, bv1.w);
        float4* O = (float4*)out;
        O[(size_t)node * 8 + 2 * c] = o0;
        O[(size_t)node * 8 + 2 * c + 1] = o1;
    }
}

extern "C" void kernel_launch(void* const* d_in, const int* in_sizes, int n_in,
                              void* d_out, int out_size, void* d_ws, size_t ws_size,
                              hipStream_t stream) {
    const float* x  = (const float*)d_in[0];
    const int*   idx = (const int*)d_in[1];
    const float* W1 = (const float*)d_in[2];
    const float* b1 = (const float*)d_in[3];
    const float* W2 = (const float*)d_in[4];
    const float* b2 = (const float*)d_in[5];
    float* out = (float*)d_out;

    const int N = in_sizes[0] / 128;   // 100000 (< 2^17, required by packing)
    const int E = in_sizes[1] / 2;     // 1600000
    const int nbuck = (N + NPB - 1) >> BSHIFT;   // 98 (<= MAXBUCK)

    // workspace layout (256B aligned)
    char* ws = (char*)d_ws;
    size_t off = 0;
    auto alloc = [&](size_t bytes) -> char* {
        char* p = ws + off;
        off = (off + bytes + 255) & ~(size_t)255;
        return p;
    };
    float* dinv     = (float*)alloc((size_t)N * 4);
    int*   row_ptr  = (int*)alloc((size_t)(N + 1) * 4);
    int*   bcounts  = (int*)alloc(MAXBUCK * 4);
    int*   bbase    = (int*)alloc((MAXBUCK + 1) * 4);
    int*   bcursor  = (int*)alloc(MAXBUCK * 4);
    int*   csr_src  = (int*)alloc((size_t)E * 4);
    ushort_t* hs1   = (ushort_t*)alloc((size_t)N * 64 * 2);  // bf16
    ushort_t* a1b   = (ushort_t*)alloc((size_t)N * 64 * 2);  // bf16
    ushort_t* hs2   = hs1;               // reuse: hs1 dead after k_agg1
    int*   edge_part = (int*)hs1;        // reuse: hs1 written only at k_gemm1

    const int ebk = (E + BLK * EPT - 1) / (BLK * EPT);  // 782

    hipMemsetAsync(bcounts, 0, MAXBUCK * 4, stream);
    k_hist<<<ebk, BLK, 0, stream>>>(idx, bcounts, E);
    k_bscan<<<1, MAXBUCK, 0, stream>>>(bcounts, bbase, bcursor, nbuck, E);
    k_part<<<ebk, BLK, 0, stream>>>(idx, bcursor, edge_part, E);
    k_csr<<<nbuck, BLK, 0, stream>>>(edge_part, bbase, row_ptr, dinv, csr_src, N, E, nbuck);

    k_gemm1<<<(N + 63) / 64, 256, 0, stream>>>(x, W1, dinv, hs1, N);
    k_agg1<<<(N + 3) / 4, 256, 0, stream>>>((const uint_t*)hs1, row_ptr, csr_src, dinv, b1, a1b, N);
    k_gemm2<<<(N + 63) / 64, 256, 0, stream>>>(a1b, W2, dinv, hs2, N);
    k_agg2<<<(N + 3) / 4, 256, 0, stream>>>((const uint_t*)hs2, row_ptr, csr_src, dinv, b2, out, N);
}

// Round 9
// 286.458 us; speedup vs baseline: 2.2772x; 1.0355x over previous
//
#include <hip/hip_runtime.h>

// GCN 2-layer: x[N,128] -> GCNConv(W1[128,64], b1) -> ReLU -> GCNConv(W2[64,32], b2)
// norm = dinv[src]*dinv[dst] factorized. CSR via bucketed multisplit (R4),
// bf16 intermediates (R5), MFMA gemms (R8).
// R9: 10 -> 6 dispatches (deterministic cells kill hist/bscan/memset; fixed
// per-bucket csr regions + deg[] kill the global scan), pk_fma/pk_add bf16
// accumulation (12 vs 16 VALU per uint4), agg unroll 4 (4 chains in flight).

#define BLK 256
#define EPT2 16          // edges/thread in k_part
#define BSHIFT 10        // nodes per bucket
#define NPB 1024         // 1 << BSHIFT
#define CELL 96          // slots per (block,bucket) cell; lambda~42, 8 sigma
#define SLOTB 18432      // csr slots per bucket; lambda~16.3K, 16 sigma
#define NBMAX 128        // >= nbuck = ceil(N/NPB) = 98

typedef unsigned int uint_t;
typedef unsigned short ushort_t;
typedef __attribute__((ext_vector_type(2))) float v2f;      // v_pk_* pair
typedef __attribute__((ext_vector_type(8))) short bf16x8;   // MFMA A/B frag
typedef __attribute__((ext_vector_type(4))) float f32x4;    // MFMA C/D frag

__device__ __forceinline__ uint_t f2bf(float x) {   // RNE float->bf16 (low 16)
    union { float f; uint_t u; } un; un.f = x;
    uint_t u = un.u;
    return (u + 0x7fffu + ((u >> 16) & 1u)) >> 16;
}

// 8 bf16 (uint4) * d += into 4 float2 accumulators (v_pk_fma_f32 path)
__device__ __forceinline__ void pkacc(v2f& a0, v2f& a1, v2f& a2, v2f& a3,
                                      uint4 v, float d) {
    v2f dd; dd.x = d; dd.y = d;
    v2f p;
    p.x = __uint_as_float(v.x << 16); p.y = __uint_as_float(v.x & 0xffff0000u); a0 += p * dd;
    p.x = __uint_as_float(v.y << 16); p.y = __uint_as_float(v.y & 0xffff0000u); a1 += p * dd;
    p.x = __uint_as_float(v.z << 16); p.y = __uint_as_float(v.z & 0xffff0000u); a2 += p * dd;
    p.x = __uint_as_float(v.w << 16); p.y = __uint_as_float(v.w & 0xffff0000u); a3 += p * dd;
}
// 8 bf16 (uint4) += into 4 float2 accumulators (v_pk_add_f32 path)
__device__ __forceinline__ void pkadd(v2f& a0, v2f& a1, v2f& a2, v2f& a3, uint4 v) {
    v2f p;
    p.x = __uint_as_float(v.x << 16); p.y = __uint_as_float(v.x & 0xffff0000u); a0 += p;
    p.x = __uint_as_float(v.y << 16); p.y = __uint_as_float(v.y & 0xffff0000u); a1 += p;
    p.x = __uint_as_float(v.z << 16); p.y = __uint_as_float(v.z & 0xffff0000u); a2 += p;
    p.x = __uint_as_float(v.w << 16); p.y = __uint_as_float(v.w & 0xffff0000u); a3 += p;
}

// int64-layout detection (wave-uniform, L2-hot)
__device__ __forceinline__ bool detect64(const int* __restrict__ idx) {
    int z = 0;
#pragma unroll
    for (int i = 1; i < 32; i += 2) z |= idx[i];
    return z == 0;
}

// ---- build pass 1: partition edges into fixed (block,bucket) cells.
// No global atomics, no init dependency: LDS count -> guarded store; cellcnt
// written unconditionally for every (block,bucket).
__global__ void k_part(const int* __restrict__ idx, int* __restrict__ edge_part,
                       int* __restrict__ cellcnt, int E, int nbuck) {
    __shared__ int h[NBMAX];
    bool is64 = detect64(idx);
    int t = threadIdx.x, blk = blockIdx.x;
    for (int i = t; i < nbuck; i += BLK) h[i] = 0;
    __syncthreads();
    int base = blk * (BLK * EPT2);
#pragma unroll 4
    for (int k = 0; k < EPT2; ++k) {
        int e = base + k * BLK + t;
        if (e < E) {
            int s = is64 ? idx[2 * e] : idx[e];
            int d = is64 ? idx[2 * (E + e)] : idx[E + e];
            int b = d >> BSHIFT;
            int slot = atomicAdd(&h[b], 1);
            if (slot < CELL)
                edge_part[(size_t)(b * gridDim.x + blk) * CELL + slot] =
                    s | ((d & (NPB - 1)) << 17);
        }
    }
    __syncthreads();
    for (int i = t; i < nbuck; i += BLK)
        cellcnt[blk * nbuck + i] = min(h[i], CELL);
}

// ---- build pass 2: one block per bucket. Count/scan/fill in LDS; emits
// row_ptr (fixed region base + local offset), deg, dinv, csr_src.
__global__ void k_csr(const int* __restrict__ edge_part, const int* __restrict__ cellcnt,
                      int* __restrict__ row_ptr, int* __restrict__ deg,
                      float* __restrict__ dinv, int* __restrict__ csr_src,
                      int N, int nbuck, int PB) {
    __shared__ int cnt[NPB];
    __shared__ int off[NPB];
    __shared__ int tsum[BLK];
    __shared__ int ccnt[512];        // PB <= 512
    int b = blockIdx.x, t = threadIdx.x;
    int node0 = b << BSHIFT;
    int nn = min(NPB, N - node0);
    for (int i = t; i < NPB; i += BLK) cnt[i] = 0;
    for (int c = t; c < PB; c += BLK) ccnt[c] = cellcnt[c * nbuck + b];
    __syncthreads();
    int w = t >> 6, l = t & 63;
    // pass 1: per-node counts
    for (int c = w; c < PB; c += 4) {
        int m = ccnt[c];
        size_t cb = (size_t)(b * PB + c) * CELL;
        for (int s = l; s < m; s += 64) {
            int p = edge_part[cb + s];
            atomicAdd(&cnt[((unsigned)p) >> 17], 1);
        }
    }
    __syncthreads();
    // exclusive scan of cnt[NPB], 4 entries/thread
    int c0 = cnt[4 * t], c1 = cnt[4 * t + 1], c2 = cnt[4 * t + 2], c3 = cnt[4 * t + 3];
    tsum[t] = c0 + c1 + c2 + c3;
    __syncthreads();
    for (int st = 1; st < BLK; st <<= 1) {
        int v = (t >= st) ? tsum[t - st] : 0;
        __syncthreads();
        tsum[t] += v;
        __syncthreads();
    }
    int ex = (t == 0) ? 0 : tsum[t - 1];
    off[4 * t] = ex;
    off[4 * t + 1] = ex + c0;
    off[4 * t + 2] = ex + c0 + c1;
    off[4 * t + 3] = ex + c0 + c1 + c2;
    __syncthreads();
    for (int i = t; i < nn; i += BLK) {
        row_ptr[node0 + i] = b * SLOTB + off[i];
        deg[node0 + i] = cnt[i];
        dinv[node0 + i] = rsqrtf((float)(cnt[i] + 1));  // +1 self-loop
    }
    __syncthreads();
    // pass 2: fill (off doubles as cursor)
    for (int c = w; c < PB; c += 4) {
        int m = ccnt[c];
        size_t cb = (size_t)(b * PB + c) * CELL;
        for (int s = l; s < m; s += 64) {
            int p = edge_part[cb + s];
            int dlo = ((unsigned)p) >> 17;
            int r = atomicAdd(&off[dlo], 1);
            csr_src[b * SLOTB + r] = p & 0x1FFFF;
        }
    }
}

// ---- layer 1 GEMM (MFMA bf16): 64 rows x 64 cols per block, 4 waves.
// hs1[i,f] = bf16((x @ W1)[i,f])  -- UNSCALED (agg1 applies dinv per edge).
__global__ __launch_bounds__(256) void k_gemm1(
        const float* __restrict__ x, const float* __restrict__ W1,
        ushort_t* __restrict__ hs1, int N) {
    __shared__ ushort_t xb[64][136];   // x tile, bf16 (+pad -> frag reads <=2-way)
    __shared__ ushort_t wb[64][136];   // W1 transposed (wb[n][k]), bf16
    int t = threadIdx.x;
    int rbase = blockIdx.x * 64;
    for (int i = t; i < 2048; i += BLK) {
        int k = i >> 4, n4 = i & 15;
        float4 w = ((const float4*)W1)[i];
        wb[4 * n4 + 0][k] = (ushort_t)f2bf(w.x);
        wb[4 * n4 + 1][k] = (ushort_t)f2bf(w.y);
        wb[4 * n4 + 2][k] = (ushort_t)f2bf(w.z);
        wb[4 * n4 + 3][k] = (ushort_t)f2bf(w.w);
    }
    for (int i = t; i < 2048; i += BLK) {
        int r = i >> 5, c4 = i & 31;
        int rr = rbase + r; if (rr >= N) rr = N - 1;
        float4 v = ((const float4*)x)[(size_t)rr * 32 + c4];
        uint2 p;
        p.x = f2bf(v.x) | (f2bf(v.y) << 16);
        p.y = f2bf(v.z) | (f2bf(v.w) << 16);
        *(uint2*)&xb[r][4 * c4] = p;
    }
    __syncthreads();
    int w = t >> 6, l = t & 63;
    int lane16 = l & 15, quad = l >> 4;
    int mrow = 16 * w + lane16;
    f32x4 acc0 = {0.f, 0.f, 0.f, 0.f}, acc1 = {0.f, 0.f, 0.f, 0.f};
    f32x4 acc2 = {0.f, 0.f, 0.f, 0.f}, acc3 = {0.f, 0.f, 0.f, 0.f};
#pragma unroll
    for (int kk = 0; kk < 4; ++kk) {
        int k0 = kk * 32 + quad * 8;
        bf16x8 a  = *(const bf16x8*)&xb[mrow][k0];
        bf16x8 b0 = *(const bf16x8*)&wb[lane16][k0];
        bf16x8 b1 = *(const bf16x8*)&wb[lane16 + 16][k0];
        bf16x8 b2 = *(const bf16x8*)&wb[lane16 + 32][k0];
        bf16x8 b3 = *(const bf16x8*)&wb[lane16 + 48][k0];
        acc0 = __builtin_amdgcn_mfma_f32_16x16x32_bf16(a, b0, acc0, 0, 0, 0);
        acc1 = __builtin_amdgcn_mfma_f32_16x16x32_bf16(a, b1, acc1, 0, 0, 0);
        acc2 = __builtin_amdgcn_mfma_f32_16x16x32_bf16(a, b2, acc2, 0, 0, 0);
        acc3 = __builtin_amdgcn_mfma_f32_16x16x32_bf16(a, b3, acc3, 0, 0, 0);
    }
    __syncthreads();
    int orow = 16 * w + quad * 4;   // D: row = quad*4+reg, col = lane16 (+16c)
    xb[orow + 0][lane16]      = (ushort_t)f2bf(acc0.x);
    xb[orow + 1][lane16]      = (ushort_t)f2bf(acc0.y);
    xb[orow + 2][lane16]      = (ushort_t)f2bf(acc0.z);
    xb[orow + 3][lane16]      = (ushort_t)f2bf(acc0.w);
    xb[orow + 0][lane16 + 16] = (ushort_t)f2bf(acc1.x);
    xb[orow + 1][lane16 + 16] = (ushort_t)f2bf(acc1.y);
    xb[orow + 2][lane16 + 16] = (ushort_t)f2bf(acc1.z);
    xb[orow + 3][lane16 + 16] = (ushort_t)f2bf(acc1.w);
    xb[orow + 0][lane16 + 32] = (ushort_t)f2bf(acc2.x);
    xb[orow + 1][lane16 + 32] = (ushort_t)f2bf(acc2.y);
    xb[orow + 2][lane16 + 32] = (ushort_t)f2bf(acc2.z);
    xb[orow + 3][lane16 + 32] = (ushort_t)f2bf(acc2.w);
    xb[orow + 0][lane16 + 48] = (ushort_t)f2bf(acc3.x);
    xb[orow + 1][lane16 + 48] = (ushort_t)f2bf(acc3.y);
    xb[orow + 2][lane16 + 48] = (ushort_t)f2bf(acc3.z);
    xb[orow + 3][lane16 + 48] = (ushort_t)f2bf(acc3.w);
    __syncthreads();
    for (int i = t; i < 512; i += BLK) {
        int r = i >> 3, c8 = i & 7;
        int rr = rbase + r;
        if (rr < N) {
            uint4 v = *(const uint4*)&xb[r][8 * c8];
            *(uint4*)&hs1[(size_t)rr * 64 + 8 * c8] = v;
        }
    }
}

// ---- layer 1 aggregation: wave/node; 8 groups x 8 lanes; unroll 4 -> 32 rows
// + 32 dinv loads in flight per wave; pk_fma accumulate (dinv[src] applied here).
__global__ void k_agg1(const uint_t* __restrict__ hs1, const int* __restrict__ row_ptr,
                       const int* __restrict__ deg, const int* __restrict__ csr_src,
                       const float* __restrict__ dinv, const float* __restrict__ b1,
                       ushort_t* __restrict__ a1b, int N) {
    int node = (blockIdx.x * blockDim.x + threadIdx.x) >> 6;
    if (node >= N) return;
    int lane = threadIdx.x & 63;
    int g = lane >> 3;   // edge slot 0..7
    int c = lane & 7;    // uint4 column: features [8c, 8c+8)
    const uint4* H = (const uint4*)hs1;
    v2f a0 = {0.f, 0.f}, a1_ = {0.f, 0.f}, a2 = {0.f, 0.f}, a3 = {0.f, 0.f};
    float dn = dinv[node];
    if (g == 0) pkacc(a0, a1_, a2, a3, H[(size_t)node * 8 + c], dn);  // self-loop
    int beg = row_ptr[node], end = beg + deg[node];
    int e = beg + g;
    for (; e + 24 < end; e += 32) {
        int j0 = csr_src[e];
        int j1 = csr_src[e + 8];
        int j2 = csr_src[e + 16];
        int j3 = csr_src[e + 24];
        float d0 = dinv[j0], d1 = dinv[j1], d2 = dinv[j2], d3 = dinv[j3];
        uint4 v0 = H[(size_t)j0 * 8 + c];
        uint4 v1 = H[(size_t)j1 * 8 + c];
        uint4 v2 = H[(size_t)j2 * 8 + c];
        uint4 v3 = H[(size_t)j3 * 8 + c];
        pkacc(a0, a1_, a2, a3, v0, d0);
        pkacc(a0, a1_, a2, a3, v1, d1);
        pkacc(a0, a1_, a2, a3, v2, d2);
        pkacc(a0, a1_, a2, a3, v3, d3);
    }
    for (; e < end; e += 8) {
        int j = csr_src[e];
        float d = dinv[j];
        pkacc(a0, a1_, a2, a3, H[(size_t)j * 8 + c], d);
    }
#pragma unroll
    for (int m = 8; m <= 32; m <<= 1) {
        a0.x += __shfl_xor(a0.x, m, 64); a0.y += __shfl_xor(a0.y, m, 64);
        a1_.x += __shfl_xor(a1_.x, m, 64); a1_.y += __shfl_xor(a1_.y, m, 64);
        a2.x += __shfl_xor(a2.x, m, 64); a2.y += __shfl_xor(a2.y, m, 64);
        a3.x += __shfl_xor(a3.x, m, 64); a3.y += __shfl_xor(a3.y, m, 64);
    }
    if (g == 0) {
        const float4* B = (const float4*)b1;
        float4 bv0 = B[2 * c], bv1 = B[2 * c + 1];
        float o0 = fmaxf(fmaf(a0.x, dn, bv0.x), 0.f);
        float o1 = fmaxf(fmaf(a0.y, dn, bv0.y), 0.f);
        float o2 = fmaxf(fmaf(a1_.x, dn, bv0.z), 0.f);
        float o3 = fmaxf(fmaf(a1_.y, dn, bv0.w), 0.f);
        float o4 = fmaxf(fmaf(a2.x, dn, bv1.x), 0.f);
        float o5 = fmaxf(fmaf(a2.y, dn, bv1.y), 0.f);
        float o6 = fmaxf(fmaf(a3.x, dn, bv1.z), 0.f);
        float o7 = fmaxf(fmaf(a3.y, dn, bv1.w), 0.f);
        uint4 o;
        o.x = f2bf(o0) | (f2bf(o1) << 16);
        o.y = f2bf(o2) | (f2bf(o3) << 16);
        o.z = f2bf(o4) | (f2bf(o5) << 16);
        o.w = f2bf(o6) | (f2bf(o7) << 16);
        ((uint4*)a1b)[(size_t)node * 8 + c] = o;
    }
}

// ---- layer 2 GEMM (MFMA bf16): 64 rows x 32 cols per block, 4 waves.
// hs2[i,f] = bf16((a1 @ W2)[i,f] * dinv[i])  -- pre-scaled (agg2 adds directly).
__global__ __launch_bounds__(256) void k_gemm2(
        const ushort_t* __restrict__ a1b, const float* __restrict__ W2,
        const float* __restrict__ dinv, ushort_t* __restrict__ hs2, int N) {
    __shared__ ushort_t ab[64][72];
    __shared__ ushort_t wb[32][72];
    int t = threadIdx.x;
    int rbase = blockIdx.x * 64;
    for (int i = t; i < 512; i += BLK) {
        int k = i >> 3, n4 = i & 7;
        float4 w = ((const float4*)W2)[i];
        wb[4 * n4 + 0][k] = (ushort_t)f2bf(w.x);
        wb[4 * n4 + 1][k] = (ushort_t)f2bf(w.y);
        wb[4 * n4 + 2][k] = (ushort_t)f2bf(w.z);
        wb[4 * n4 + 3][k] = (ushort_t)f2bf(w.w);
    }
    for (int i = t; i < 512; i += BLK) {
        int r = i >> 3, c8 = i & 7;
        int rr = rbase + r; if (rr >= N) rr = N - 1;
        uint4 v = ((const uint4*)a1b)[(size_t)rr * 8 + c8];
        *(uint4*)&ab[r][8 * c8] = v;
    }
    __syncthreads();
    int w = t >> 6, l = t & 63;
    int lane16 = l & 15, quad = l >> 4;
    int mrow = 16 * w + lane16;
    f32x4 acc0 = {0.f, 0.f, 0.f, 0.f}, acc1 = {0.f, 0.f, 0.f, 0.f};
#pragma unroll
    for (int kk = 0; kk < 2; ++kk) {
        int k0 = kk * 32 + quad * 8;
        bf16x8 a  = *(const bf16x8*)&ab[mrow][k0];
        bf16x8 b0 = *(const bf16x8*)&wb[lane16][k0];
        bf16x8 b1 = *(const bf16x8*)&wb[lane16 + 16][k0];
        acc0 = __builtin_amdgcn_mfma_f32_16x16x32_bf16(a, b0, acc0, 0, 0, 0);
        acc1 = __builtin_amdgcn_mfma_f32_16x16x32_bf16(a, b1, acc1, 0, 0, 0);
    }
    __syncthreads();
    int orow = 16 * w + quad * 4;
    float d0 = dinv[min(rbase + orow + 0, N - 1)];
    float d1 = dinv[min(rbase + orow + 1, N - 1)];
    float d2 = dinv[min(rbase + orow + 2, N - 1)];
    float d3 = dinv[min(rbase + orow + 3, N - 1)];
    ab[orow + 0][lane16]      = (ushort_t)f2bf(acc0.x * d0);
    ab[orow + 1][lane16]      = (ushort_t)f2bf(acc0.y * d1);
    ab[orow + 2][lane16]      = (ushort_t)f2bf(acc0.z * d2);
    ab[orow + 3][lane16]      = (ushort_t)f2bf(acc0.w * d3);
    ab[orow + 0][lane16 + 16] = (ushort_t)f2bf(acc1.x * d0);
    ab[orow + 1][lane16 + 16] = (ushort_t)f2bf(acc1.y * d1);
    ab[orow + 2][lane16 + 16] = (ushort_t)f2bf(acc1.z * d2);
    ab[orow + 3][lane16 + 16] = (ushort_t)f2bf(acc1.w * d3);
    __syncthreads();
    for (int i = t; i < 256; i += BLK) {
        int r = i >> 2, c4 = i & 3;
        int rr = rbase + r;
        if (rr < N) {
            uint4 v = *(const uint4*)&ab[r][8 * c4];
            *(uint4*)&hs2[(size_t)rr * 32 + 8 * c4] = v;
        }
    }
}

// ---- layer 2 aggregation: 16 groups x 4 lanes; unroll 4 -> 64 rows in flight;
// pk_add accumulate (hs2 pre-scaled).
__global__ void k_agg2(const uint_t* __restrict__ hs2, const int* __restrict__ row_ptr,
                       const int* __restrict__ deg, const int* __restrict__ csr_src,
                       const float* __restrict__ dinv, const float* __restrict__ b2,
                       float* __restrict__ out, int N) {
    int node = (blockIdx.x * blockDim.x + threadIdx.x) >> 6;
    if (node >= N) return;
    int lane = threadIdx.x & 63;
    int g = lane >> 2;   // edge slot 0..15
    int c = lane & 3;    // uint4 column: features [8c, 8c+8)
    const uint4* H = (const uint4*)hs2;
    v2f a0 = {0.f, 0.f}, a1_ = {0.f, 0.f}, a2 = {0.f, 0.f}, a3 = {0.f, 0.f};
    if (g == 0) pkadd(a0, a1_, a2, a3, H[(size_t)node * 4 + c]);  // self-loop
    int beg = row_ptr[node], end = beg + deg[node];
    int e = beg + g;
    for (; e + 48 < end; e += 64) {
        int j0 = csr_src[e];
        int j1 = csr_src[e + 16];
        int j2 = csr_src[e + 32];
        int j3 = csr_src[e + 48];
        uint4 v0 = H[(size_t)j0 * 4 + c];
        uint4 v1 = H[(size_t)j1 * 4 + c];
        uint4 v2 = H[(size_t)j2 * 4 + c];
        uint4 v3 = H[(size_t)j3 * 4 + c];
        pkadd(a0, a1_, a2, a3, v0);
        pkadd(a0, a1_, a2, a3, v1);
        pkadd(a0, a1_, a2, a3, v2);
        pkadd(a0, a1_, a2, a3, v3);
    }
    for (; e < end; e += 16) {
        int j = csr_src[e];
        pkadd(a0, a1_, a2, a3, H[(size_t)j * 4 + c]);
    }
#pragma unroll
    for (int m = 4; m <= 32; m <<= 1) {
        a0.x += __shfl_xor(a0.x, m, 64); a0.y += __shfl_xor(a0.y, m, 64);
        a1_.x += __shfl_xor(a1_.x, m, 64); a1_.y += __shfl_xor(a1_.y, m, 64);
        a2.x += __shfl_xor(a2.x, m, 64); a2.y += __shfl_xor(a2.y, m, 64);
        a3.x += __shfl_xor(a3.x, m, 64); a3.y += __shfl_xor(a3.y, m, 64);
    }
    if (g == 0) {
        float s = dinv[node];
        const float4* B = (const float4*)b2;
        float4 bv0 = B[2 * c], bv1 = B[2 * c + 1];
        float4 o0, o1;
        o0.x = fmaf(a0.x, s, bv0.x);
        o0.y = fmaf(a0.y, s, bv0.y);
        o0.z = fmaf(a1_.x, s, bv0.z);
        o0.w = fmaf(a1_.y, s, bv0.w);
        o1.x = fmaf(a2.x, s, bv1.x);
        o1.y = fmaf(a2.y, s, bv1.y);
        o1.z = fmaf(a3.x, s, bv1.z);
        o1.w = fmaf(a3.y, s, bv1.w);
        float4* O = (float4*)out;
        O[(size_t)node * 8 + 2 * c] = o0;
        O[(size_t)node * 8 + 2 * c + 1] = o1;
    }
}

extern "C" void kernel_launch(void* const* d_in, const int* in_sizes, int n_in,
                              void* d_out, int out_size, void* d_ws, size_t ws_size,
                              hipStream_t stream) {
    const float* x  = (const float*)d_in[0];
    const int*   idx = (const int*)d_in[1];
    const float* W1 = (const float*)d_in[2];
    const float* b1 = (const float*)d_in[3];
    const float* W2 = (const float*)d_in[4];
    const float* b2 = (const float*)d_in[5];
    float* out = (float*)d_out;

    const int N = in_sizes[0] / 128;   // 100000 (< 2^17, required by packing)
    const int E = in_sizes[1] / 2;     // 1600000
    const int nbuck = (N + NPB - 1) >> BSHIFT;        // 98 (<= NBMAX)
    const int PB = (E + BLK * EPT2 - 1) / (BLK * EPT2);  // 392 (<= 512)

    // workspace layout (256B aligned), ~36 MB total
    char* ws = (char*)d_ws;
    size_t off = 0;
    auto alloc = [&](size_t bytes) -> char* {
        char* p = ws + off;
        off = (off + bytes + 255) & ~(size_t)255;
        return p;
    };
    float* dinv     = (float*)alloc((size_t)N * 4);
    int*   row_ptr  = (int*)alloc((size_t)N * 4);
    int*   deg      = (int*)alloc((size_t)N * 4);
    int*   cellcnt  = (int*)alloc((size_t)PB * nbuck * 4);
    int*   csr_src  = (int*)alloc((size_t)nbuck * SLOTB * 4);
    size_t ep_bytes = (size_t)nbuck * PB * CELL * 4;          // 14.75 MB
    size_t h1_bytes = (size_t)N * 64 * 2;                     // 12.8 MB
    int*   edge_part = (int*)alloc(ep_bytes > h1_bytes ? ep_bytes : h1_bytes);
    ushort_t* a1b   = (ushort_t*)alloc((size_t)N * 64 * 2);
    ushort_t* hs1   = (ushort_t*)edge_part;   // alias: edge_part dead after k_csr
    ushort_t* hs2   = hs1;                    // alias: hs1 dead after k_agg1

    k_part<<<PB, BLK, 0, stream>>>(idx, edge_part, cellcnt, E, nbuck);
    k_csr<<<nbuck, BLK, 0, stream>>>(edge_part, cellcnt, row_ptr, deg, dinv,
                                     csr_src, N, nbuck, PB);
    k_gemm1<<<(N + 63) / 64, BLK, 0, stream>>>(x, W1, hs1, N);
    k_agg1<<<(N + 3) / 4, BLK, 0, stream>>>((const uint_t*)hs1, row_ptr, deg,
                                            csr_src, dinv, b1, a1b, N);
    k_gemm2<<<(N + 63) / 64, BLK, 0, stream>>>(a1b, W2, dinv, hs2, N);
    k_agg2<<<(N + 3) / 4, BLK, 0, stream>>>((const uint_t*)hs2, row_ptr, deg,
                                            csr_src, dinv, b2, out, N);
}

// Round 10
// 261.465 us; speedup vs baseline: 2.4949x; 1.0956x over previous
//
#include <hip/hip_runtime.h>

// GCN 2-layer: x[N,128] -> GCNConv(W1[128,64], b1) -> ReLU -> GCNConv(W2[64,32], b2)
// norm = dinv[src]*dinv[dst] factorized. Bucketed multisplit build (R4), bf16
// intermediates (R5), MFMA gemms (R8), pk-math aggs (R9).
// R10: k_csr back to DENSE per-bucket edge segments (R9 cells serialized it:
// 3.8% occupancy, one load-chain per wave). k_part reserves contiguous runs via
// global cursors at fixed bases b*SLOTB (392B memset, no hist/scan kernels);
// k_csr runs 1024 thr/block, 16 indep edges/thread/pass.

#define BLK 256
#define BLKC 1024        // k_csr block size
#define EPT 8            // edges/thread in k_part
#define BSHIFT 10        // nodes per bucket
#define NPB 1024         // 1 << BSHIFT
#define SLOTB 18432      // edge slots per bucket; lambda~16.3K, 16 sigma
#define NBMAX 128        // >= nbuck = ceil(N/NPB) = 98

typedef unsigned int uint_t;
typedef unsigned short ushort_t;
typedef __attribute__((ext_vector_type(2))) float v2f;      // v_pk_* pair
typedef __attribute__((ext_vector_type(8))) short bf16x8;   // MFMA A/B frag
typedef __attribute__((ext_vector_type(4))) float f32x4;    // MFMA C/D frag

__device__ __forceinline__ uint_t f2bf(float x) {   // RNE float->bf16 (low 16)
    union { float f; uint_t u; } un; un.f = x;
    uint_t u = un.u;
    return (u + 0x7fffu + ((u >> 16) & 1u)) >> 16;
}

// 8 bf16 (uint4) * d += into 4 float2 accumulators (v_pk_fma_f32 path)
__device__ __forceinline__ void pkacc(v2f& a0, v2f& a1, v2f& a2, v2f& a3,
                                      uint4 v, float d) {
    v2f dd; dd.x = d; dd.y = d;
    v2f p;
    p.x = __uint_as_float(v.x << 16); p.y = __uint_as_float(v.x & 0xffff0000u); a0 += p * dd;
    p.x = __uint_as_float(v.y << 16); p.y = __uint_as_float(v.y & 0xffff0000u); a1 += p * dd;
    p.x = __uint_as_float(v.z << 16); p.y = __uint_as_float(v.z & 0xffff0000u); a2 += p * dd;
    p.x = __uint_as_float(v.w << 16); p.y = __uint_as_float(v.w & 0xffff0000u); a3 += p * dd;
}
// 8 bf16 (uint4) += into 4 float2 accumulators (v_pk_add_f32 path)
__device__ __forceinline__ void pkadd(v2f& a0, v2f& a1, v2f& a2, v2f& a3, uint4 v) {
    v2f p;
    p.x = __uint_as_float(v.x << 16); p.y = __uint_as_float(v.x & 0xffff0000u); a0 += p;
    p.x = __uint_as_float(v.y << 16); p.y = __uint_as_float(v.y & 0xffff0000u); a1 += p;
    p.x = __uint_as_float(v.z << 16); p.y = __uint_as_float(v.z & 0xffff0000u); a2 += p;
    p.x = __uint_as_float(v.w << 16); p.y = __uint_as_float(v.w & 0xffff0000u); a3 += p;
}

// int64-layout detection (wave-uniform, L2-hot)
__device__ __forceinline__ bool detect64(const int* __restrict__ idx) {
    int z = 0;
#pragma unroll
    for (int i = 1; i < 32; i += 2) z |= idx[i];
    return z == 0;
}

// ---- build pass 1: partition edges into DENSE per-bucket segments.
// LDS histogram -> one global cursor atomicAdd per (block,bucket) to reserve a
// contiguous run at fixed base b*SLOTB -> grouped stores (L2 write-combining).
__global__ void k_part(const int* __restrict__ idx, int* __restrict__ bcursor,
                       int* __restrict__ edge_part, int E, int nbuck) {
    __shared__ int h[NBMAX];
    __shared__ int rb[NBMAX];
    bool is64 = detect64(idx);
    int t = threadIdx.x, blk = blockIdx.x;
    for (int i = t; i < nbuck; i += BLK) h[i] = 0;
    __syncthreads();
    int base = blk * (BLK * EPT) + t;
    int dst[EPT], src[EPT];
#pragma unroll
    for (int k = 0; k < EPT; ++k) {
        int e = base + k * BLK;
        if (e < E) {
            dst[k] = is64 ? idx[2 * (E + e)] : idx[E + e];
            src[k] = is64 ? idx[2 * e] : idx[e];
            atomicAdd(&h[dst[k] >> BSHIFT], 1);
        } else {
            dst[k] = -1;
        }
    }
    __syncthreads();
    for (int i = t; i < nbuck; i += BLK) {
        int c = h[i];
        rb[i] = c ? atomicAdd(&bcursor[i], c) : 0;
        h[i] = 0;
    }
    __syncthreads();
#pragma unroll
    for (int k = 0; k < EPT; ++k) {
        if (dst[k] >= 0) {
            int b = dst[k] >> BSHIFT;
            int r = atomicAdd(&h[b], 1);
            edge_part[(size_t)b * SLOTB + rb[b] + r] =
                src[k] | ((dst[k] & (NPB - 1)) << 17);
        }
    }
}

// ---- build pass 2: one 1024-thread block per bucket; dense coalesced edge
// reads, 16 indep loads/thread/pass; count/scan/fill in LDS; emits row_ptr,
// deg, dinv, csr_src.
__global__ __launch_bounds__(BLKC) void k_csr(
        const int* __restrict__ edge_part, const int* __restrict__ bcursor,
        int* __restrict__ row_ptr, int* __restrict__ deg, float* __restrict__ dinv,
        int* __restrict__ csr_src, int N, int nbuck) {
    __shared__ int cnt[NPB];
    __shared__ int off[NPB];
    int b = blockIdx.x, t = threadIdx.x;
    int node0 = b << BSHIFT;
    int nn = min(NPB, N - node0);
    int m = bcursor[b];                   // total edges in this bucket
    size_t ebase = (size_t)b * SLOTB;
    cnt[t] = 0;
    __syncthreads();
    for (int e = t; e < m; e += BLKC)
        atomicAdd(&cnt[((unsigned)edge_part[ebase + e]) >> 17], 1);
    __syncthreads();
    // inclusive scan of cnt[1024] (1 entry/thread) -> exclusive offsets
    off[t] = cnt[t];
    __syncthreads();
    for (int st = 1; st < BLKC; st <<= 1) {
        int v = (t >= st) ? off[t - st] : 0;
        __syncthreads();
        off[t] += v;
        __syncthreads();
    }
    int excl = off[t] - cnt[t];
    off[t] = excl;                        // own-entry overwrite, no cross-read
    if (t < nn) {
        row_ptr[node0 + t] = (int)(ebase + excl);
        deg[node0 + t] = cnt[t];
        dinv[node0 + t] = rsqrtf((float)(cnt[t] + 1));  // +1 self-loop
    }
    __syncthreads();
    for (int e = t; e < m; e += BLKC) {
        int p = edge_part[ebase + e];
        int dlo = ((unsigned)p) >> 17;
        int r = atomicAdd(&off[dlo], 1);
        csr_src[ebase + r] = p & 0x1FFFF;
    }
}

// ---- layer 1 GEMM (MFMA bf16): 64 rows x 64 cols per block, 4 waves.
// hs1[i,f] = bf16((x @ W1)[i,f])  -- UNSCALED (agg1 applies dinv per edge).
__global__ __launch_bounds__(256) void k_gemm1(
        const float* __restrict__ x, const float* __restrict__ W1,
        ushort_t* __restrict__ hs1, int N) {
    __shared__ ushort_t xb[64][136];   // x tile, bf16 (+pad -> frag reads <=2-way)
    __shared__ ushort_t wb[64][136];   // W1 transposed (wb[n][k]), bf16
    int t = threadIdx.x;
    int rbase = blockIdx.x * 64;
    for (int i = t; i < 2048; i += BLK) {
        int k = i >> 4, n4 = i & 15;
        float4 w = ((const float4*)W1)[i];
        wb[4 * n4 + 0][k] = (ushort_t)f2bf(w.x);
        wb[4 * n4 + 1][k] = (ushort_t)f2bf(w.y);
        wb[4 * n4 + 2][k] = (ushort_t)f2bf(w.z);
        wb[4 * n4 + 3][k] = (ushort_t)f2bf(w.w);
    }
    for (int i = t; i < 2048; i += BLK) {
        int r = i >> 5, c4 = i & 31;
        int rr = rbase + r; if (rr >= N) rr = N - 1;
        float4 v = ((const float4*)x)[(size_t)rr * 32 + c4];
        uint2 p;
        p.x = f2bf(v.x) | (f2bf(v.y) << 16);
        p.y = f2bf(v.z) | (f2bf(v.w) << 16);
        *(uint2*)&xb[r][4 * c4] = p;
    }
    __syncthreads();
    int w = t >> 6, l = t & 63;
    int lane16 = l & 15, quad = l >> 4;
    int mrow = 16 * w + lane16;
    f32x4 acc0 = {0.f, 0.f, 0.f, 0.f}, acc1 = {0.f, 0.f, 0.f, 0.f};
    f32x4 acc2 = {0.f, 0.f, 0.f, 0.f}, acc3 = {0.f, 0.f, 0.f, 0.f};
#pragma unroll
    for (int kk = 0; kk < 4; ++kk) {
        int k0 = kk * 32 + quad * 8;
        bf16x8 a  = *(const bf16x8*)&xb[mrow][k0];
        bf16x8 b0 = *(const bf16x8*)&wb[lane16][k0];
        bf16x8 b1 = *(const bf16x8*)&wb[lane16 + 16][k0];
        bf16x8 b2 = *(const bf16x8*)&wb[lane16 + 32][k0];
        bf16x8 b3 = *(const bf16x8*)&wb[lane16 + 48][k0];
        acc0 = __builtin_amdgcn_mfma_f32_16x16x32_bf16(a, b0, acc0, 0, 0, 0);
        acc1 = __builtin_amdgcn_mfma_f32_16x16x32_bf16(a, b1, acc1, 0, 0, 0);
        acc2 = __builtin_amdgcn_mfma_f32_16x16x32_bf16(a, b2, acc2, 0, 0, 0);
        acc3 = __builtin_amdgcn_mfma_f32_16x16x32_bf16(a, b3, acc3, 0, 0, 0);
    }
    __syncthreads();
    int orow = 16 * w + quad * 4;   // D: row = quad*4+reg, col = lane16 (+16c)
    xb[orow + 0][lane16]      = (ushort_t)f2bf(acc0.x);
    xb[orow + 1][lane16]      = (ushort_t)f2bf(acc0.y);
    xb[orow + 2][lane16]      = (ushort_t)f2bf(acc0.z);
    xb[orow + 3][lane16]      = (ushort_t)f2bf(acc0.w);
    xb[orow + 0][lane16 + 16] = (ushort_t)f2bf(acc1.x);
    xb[orow + 1][lane16 + 16] = (ushort_t)f2bf(acc1.y);
    xb[orow + 2][lane16 + 16] = (ushort_t)f2bf(acc1.z);
    xb[orow + 3][lane16 + 16] = (ushort_t)f2bf(acc1.w);
    xb[orow + 0][lane16 + 32] = (ushort_t)f2bf(acc2.x);
    xb[orow + 1][lane16 + 32] = (ushort_t)f2bf(acc2.y);
    xb[orow + 2][lane16 + 32] = (ushort_t)f2bf(acc2.z);
    xb[orow + 3][lane16 + 32] = (ushort_t)f2bf(acc2.w);
    xb[orow + 0][lane16 + 48] = (ushort_t)f2bf(acc3.x);
    xb[orow + 1][lane16 + 48] = (ushort_t)f2bf(acc3.y);
    xb[orow + 2][lane16 + 48] = (ushort_t)f2bf(acc3.z);
    xb[orow + 3][lane16 + 48] = (ushort_t)f2bf(acc3.w);
    __syncthreads();
    for (int i = t; i < 512; i += BLK) {
        int r = i >> 3, c8 = i & 7;
        int rr = rbase + r;
        if (rr < N) {
            uint4 v = *(const uint4*)&xb[r][8 * c8];
            *(uint4*)&hs1[(size_t)rr * 64 + 8 * c8] = v;
        }
    }
}

// ---- layer 1 aggregation: wave/node; 8 groups x 8 lanes; unroll 4 -> 32 rows
// + 32 dinv loads in flight per wave; pk_fma accumulate (dinv[src] applied here).
__global__ void k_agg1(const uint_t* __restrict__ hs1, const int* __restrict__ row_ptr,
                       const int* __restrict__ deg, const int* __restrict__ csr_src,
                       const float* __restrict__ dinv, const float* __restrict__ b1,
                       ushort_t* __restrict__ a1b, int N) {
    int node = (blockIdx.x * blockDim.x + threadIdx.x) >> 6;
    if (node >= N) return;
    int lane = threadIdx.x & 63;
    int g = lane >> 3;   // edge slot 0..7
    int c = lane & 7;    // uint4 column: features [8c, 8c+8)
    const uint4* H = (const uint4*)hs1;
    v2f a0 = {0.f, 0.f}, a1_ = {0.f, 0.f}, a2 = {0.f, 0.f}, a3 = {0.f, 0.f};
    float dn = dinv[node];
    if (g == 0) pkacc(a0, a1_, a2, a3, H[(size_t)node * 8 + c], dn);  // self-loop
    int beg = row_ptr[node], end = beg + deg[node];
    int e = beg + g;
    for (; e + 24 < end; e += 32) {
        int j0 = csr_src[e];
        int j1 = csr_src[e + 8];
        int j2 = csr_src[e + 16];
        int j3 = csr_src[e + 24];
        float d0 = dinv[j0], d1 = dinv[j1], d2 = dinv[j2], d3 = dinv[j3];
        uint4 v0 = H[(size_t)j0 * 8 + c];
        uint4 v1 = H[(size_t)j1 * 8 + c];
        uint4 v2 = H[(size_t)j2 * 8 + c];
        uint4 v3 = H[(size_t)j3 * 8 + c];
        pkacc(a0, a1_, a2, a3, v0, d0);
        pkacc(a0, a1_, a2, a3, v1, d1);
        pkacc(a0, a1_, a2, a3, v2, d2);
        pkacc(a0, a1_, a2, a3, v3, d3);
    }
    for (; e < end; e += 8) {
        int j = csr_src[e];
        float d = dinv[j];
        pkacc(a0, a1_, a2, a3, H[(size_t)j * 8 + c], d);
    }
#pragma unroll
    for (int m = 8; m <= 32; m <<= 1) {
        a0.x += __shfl_xor(a0.x, m, 64); a0.y += __shfl_xor(a0.y, m, 64);
        a1_.x += __shfl_xor(a1_.x, m, 64); a1_.y += __shfl_xor(a1_.y, m, 64);
        a2.x += __shfl_xor(a2.x, m, 64); a2.y += __shfl_xor(a2.y, m, 64);
        a3.x += __shfl_xor(a3.x, m, 64); a3.y += __shfl_xor(a3.y, m, 64);
    }
    if (g == 0) {
        const float4* B = (const float4*)b1;
        float4 bv0 = B[2 * c], bv1 = B[2 * c + 1];
        float o0 = fmaxf(fmaf(a0.x, dn, bv0.x), 0.f);
        float o1 = fmaxf(fmaf(a0.y, dn, bv0.y), 0.f);
        float o2 = fmaxf(fmaf(a1_.x, dn, bv0.z), 0.f);
        float o3 = fmaxf(fmaf(a1_.y, dn, bv0.w), 0.f);
        float o4 = fmaxf(fmaf(a2.x, dn, bv1.x), 0.f);
        float o5 = fmaxf(fmaf(a2.y, dn, bv1.y), 0.f);
        float o6 = fmaxf(fmaf(a3.x, dn, bv1.z), 0.f);
        float o7 = fmaxf(fmaf(a3.y, dn, bv1.w), 0.f);
        uint4 o;
        o.x = f2bf(o0) | (f2bf(o1) << 16);
        o.y = f2bf(o2) | (f2bf(o3) << 16);
        o.z = f2bf(o4) | (f2bf(o5) << 16);
        o.w = f2bf(o6) | (f2bf(o7) << 16);
        ((uint4*)a1b)[(size_t)node * 8 + c] = o;
    }
}

// ---- layer 2 GEMM (MFMA bf16): 64 rows x 32 cols per block, 4 waves.
// hs2[i,f] = bf16((a1 @ W2)[i,f] * dinv[i])  -- pre-scaled (agg2 adds directly).
__global__ __launch_bounds__(256) void k_gemm2(
        const ushort_t* __restrict__ a1b, const float* __restrict__ W2,
        const float* __restrict__ dinv, ushort_t* __restrict__ hs2, int N) {
    __shared__ ushort_t ab[64][72];
    __shared__ ushort_t wb[32][72];
    int t = threadIdx.x;
    int rbase = blockIdx.x * 64;
    for (int i = t; i < 512; i += BLK) {
        int k = i >> 3, n4 = i & 7;
        float4 w = ((const float4*)W2)[i];
        wb[4 * n4 + 0][k] = (ushort_t)f2bf(w.x);
        wb[4 * n4 + 1][k] = (ushort_t)f2bf(w.y);
        wb[4 * n4 + 2][k] = (ushort_t)f2bf(w.z);
        wb[4 * n4 + 3][k] = (ushort_t)f2bf(w.w);
    }
    for (int i = t; i < 512; i += BLK) {
        int r = i >> 3, c8 = i & 7;
        int rr = rbase + r; if (rr >= N) rr = N - 1;
        uint4 v = ((const uint4*)a1b)[(size_t)rr * 8 + c8];
        *(uint4*)&ab[r][8 * c8] = v;
    }
    __syncthreads();
    int w = t >> 6, l = t & 63;
    int lane16 = l & 15, quad = l >> 4;
    int mrow = 16 * w + lane16;
    f32x4 acc0 = {0.f, 0.f, 0.f, 0.f}, acc1 = {0.f, 0.f, 0.f, 0.f};
#pragma unroll
    for (int kk = 0; kk < 2; ++kk) {
        int k0 = kk * 32 + quad * 8;
        bf16x8 a  = *(const bf16x8*)&ab[mrow][k0];
        bf16x8 b0 = *(const bf16x8*)&wb[lane16][k0];
        bf16x8 b1 = *(const bf16x8*)&wb[lane16 + 16][k0];
        acc0 = __builtin_amdgcn_mfma_f32_16x16x32_bf16(a, b0, acc0, 0, 0, 0);
        acc1 = __builtin_amdgcn_mfma_f32_16x16x32_bf16(a, b1, acc1, 0, 0, 0);
    }
    __syncthreads();
    int orow = 16 * w + quad * 4;
    float d0 = dinv[min(rbase + orow + 0, N - 1)];
    float d1 = dinv[min(rbase + orow + 1, N - 1)];
    float d2 = dinv[min(rbase + orow + 2, N - 1)];
    float d3 = dinv[min(rbase + orow + 3, N - 1)];
    ab[orow + 0][lane16]      = (ushort_t)f2bf(acc0.x * d0);
    ab[orow + 1][lane16]      = (ushort_t)f2bf(acc0.y * d1);
    ab[orow + 2][lane16]      = (ushort_t)f2bf(acc0.z * d2);
    ab[orow + 3][lane16]      = (ushort_t)f2bf(acc0.w * d3);
    ab[orow + 0][lane16 + 16] = (ushort_t)f2bf(acc1.x * d0);
    ab[orow + 1][lane16 + 16] = (ushort_t)f2bf(acc1.y * d1);
    ab[orow + 2][lane16 + 16] = (ushort_t)f2bf(acc1.z * d2);
    ab[orow + 3][lane16 + 16] = (ushort_t)f2bf(acc1.w * d3);
    __syncthreads();
    for (int i = t; i < 256; i += BLK) {
        int r = i >> 2, c4 = i & 3;
        int rr = rbase + r;
        if (rr < N) {
            uint4 v = *(const uint4*)&ab[r][8 * c4];
            *(uint4*)&hs2[(size_t)rr * 32 + 8 * c4] = v;
        }
    }
}

// ---- layer 2 aggregation: 16 groups x 4 lanes; unroll 4 -> 64 rows in flight;
// pk_add accumulate (hs2 pre-scaled).
__global__ void k_agg2(const uint_t* __restrict__ hs2, const int* __restrict__ row_ptr,
                       const int* __restrict__ deg, const int* __restrict__ csr_src,
                       const float* __restrict__ dinv, const float* __restrict__ b2,
                       float* __restrict__ out, int N) {
    int node = (blockIdx.x * blockDim.x + threadIdx.x) >> 6;
    if (node >= N) return;
    int lane = threadIdx.x & 63;
    int g = lane >> 2;   // edge slot 0..15
    int c = lane & 3;    // uint4 column: features [8c, 8c+8)
    const uint4* H = (const uint4*)hs2;
    v2f a0 = {0.f, 0.f}, a1_ = {0.f, 0.f}, a2 = {0.f, 0.f}, a3 = {0.f, 0.f};
    if (g == 0) pkadd(a0, a1_, a2, a3, H[(size_t)node * 4 + c]);  // self-loop
    int beg = row_ptr[node], end = beg + deg[node];
    int e = beg + g;
    for (; e + 48 < end; e += 64) {
        int j0 = csr_src[e];
        int j1 = csr_src[e + 16];
        int j2 = csr_src[e + 32];
        int j3 = csr_src[e + 48];
        uint4 v0 = H[(size_t)j0 * 4 + c];
        uint4 v1 = H[(size_t)j1 * 4 + c];
        uint4 v2 = H[(size_t)j2 * 4 + c];
        uint4 v3 = H[(size_t)j3 * 4 + c];
        pkadd(a0, a1_, a2, a3, v0);
        pkadd(a0, a1_, a2, a3, v1);
        pkadd(a0, a1_, a2, a3, v2);
        pkadd(a0, a1_, a2, a3, v3);
    }
    for (; e < end; e += 16) {
        int j = csr_src[e];
        pkadd(a0, a1_, a2, a3, H[(size_t)j * 4 + c]);
    }
#pragma unroll
    for (int m = 4; m <= 32; m <<= 1) {
        a0.x += __shfl_xor(a0.x, m, 64); a0.y += __shfl_xor(a0.y, m, 64);
        a1_.x += __shfl_xor(a1_.x, m, 64); a1_.y += __shfl_xor(a1_.y, m, 64);
        a2.x += __shfl_xor(a2.x, m, 64); a2.y += __shfl_xor(a2.y, m, 64);
        a3.x += __shfl_xor(a3.x, m, 64); a3.y += __shfl_xor(a3.y, m, 64);
    }
    if (g == 0) {
        float s = dinv[node];
        const float4* B = (const float4*)b2;
        float4 bv0 = B[2 * c], bv1 = B[2 * c + 1];
        float4 o0, o1;
        o0.x = fmaf(a0.x, s, bv0.x);
        o0.y = fmaf(a0.y, s, bv0.y);
        o0.z = fmaf(a1_.x, s, bv0.z);
        o0.w = fmaf(a1_.y, s, bv0.w);
        o1.x = fmaf(a2.x, s, bv1.x);
        o1.y = fmaf(a2.y, s, bv1.y);
        o1.z = fmaf(a3.x, s, bv1.z);
        o1.w = fmaf(a3.y, s, bv1.w);
        float4* O = (float4*)out;
        O[(size_t)node * 8 + 2 * c] = o0;
        O[(size_t)node * 8 + 2 * c + 1] = o1;
    }
}

extern "C" void kernel_launch(void* const* d_in, const int* in_sizes, int n_in,
                              void* d_out, int out_size, void* d_ws, size_t ws_size,
                              hipStream_t stream) {
    const float* x  = (const float*)d_in[0];
    const int*   idx = (const int*)d_in[1];
    const float* W1 = (const float*)d_in[2];
    const float* b1 = (const float*)d_in[3];
    const float* W2 = (const float*)d_in[4];
    const float* b2 = (const float*)d_in[5];
    float* out = (float*)d_out;

    const int N = in_sizes[0] / 128;   // 100000 (< 2^17, required by packing)
    const int E = in_sizes[1] / 2;     // 1600000
    const int nbuck = (N + NPB - 1) >> BSHIFT;        // 98 (<= NBMAX)
    const int PB = (E + BLK * EPT - 1) / (BLK * EPT); // 782

    // workspace layout (256B aligned)
    char* ws = (char*)d_ws;
    size_t off = 0;
    auto alloc = [&](size_t bytes) -> char* {
        char* p = ws + off;
        off = (off + bytes + 255) & ~(size_t)255;
        return p;
    };
    float* dinv     = (float*)alloc((size_t)N * 4);
    int*   row_ptr  = (int*)alloc((size_t)N * 4);
    int*   deg      = (int*)alloc((size_t)N * 4);
    int*   bcursor  = (int*)alloc((size_t)nbuck * 4);
    int*   csr_src  = (int*)alloc((size_t)nbuck * SLOTB * 4);   // 7.2 MB
    size_t ep_bytes = (size_t)nbuck * SLOTB * 4;                // 7.2 MB
    size_t h1_bytes = (size_t)N * 64 * 2;                       // 12.8 MB
    int*   edge_part = (int*)alloc(ep_bytes > h1_bytes ? ep_bytes : h1_bytes);
    ushort_t* a1b   = (ushort_t*)alloc((size_t)N * 64 * 2);
    ushort_t* hs1   = (ushort_t*)edge_part;   // alias: edge_part dead after k_csr
    ushort_t* hs2   = hs1;                    // alias: hs1 dead after k_agg1

    hipMemsetAsync(bcursor, 0, (size_t)nbuck * 4, stream);
    k_part<<<PB, BLK, 0, stream>>>(idx, bcursor, edge_part, E, nbuck);
    k_csr<<<nbuck, BLKC, 0, stream>>>(edge_part, bcursor, row_ptr, deg, dinv,
                                      csr_src, N, nbuck);
    k_gemm1<<<(N + 63) / 64, BLK, 0, stream>>>(x, W1, hs1, N);
    k_agg1<<<(N + 3) / 4, BLK, 0, stream>>>((const uint_t*)hs1, row_ptr, deg,
                                            csr_src, dinv, b1, a1b, N);
    k_gemm2<<<(N + 63) / 64, BLK, 0, stream>>>(a1b, W2, dinv, hs2, N);
    k_agg2<<<(N + 3) / 4, BLK, 0, stream>>>((const uint_t*)hs2, row_ptr, deg,
                                            csr_src, dinv, b2, out, N);
}